// Round 1
// baseline (790.326 us; speedup 1.0000x reference)
//
#include <hip/hip_runtime.h>
#include <math.h>

#define GG     384
#define HALFG  192
#define SZc    384
#define SYZc   147456
#define SXYZc  56623104
#define CC     128
#define PP     343
#define KK     125
#define TBITS  20
#define TSLOTS (1 << TBITS)
#define TMASK  (TSLOTS - 1)
#define CAPK   2048
#define CAPP   1024
#define EPSc   1e-5f

__device__ __forceinline__ unsigned hash32(int code) {
    unsigned h = (unsigned)code;
    h ^= h >> 16; h *= 0x7feb352du;
    h ^= h >> 15; h *= 0x846ca68bu;
    h ^= h >> 16;
    return h & TMASK;
}

// ---- build sp-voxel hash: code -> row ----
__global__ void k_buildB(const int* __restrict__ spc, int2* tabB, int Nv) {
    int i = blockIdx.x * 256 + threadIdx.x;
    if (i >= Nv) return;
    int b = spc[i * 4 + 0];
    int x = (spc[i * 4 + 1] >> 1) + HALFG;
    int y = (spc[i * 4 + 2] >> 1) + HALFG;
    int z = (spc[i * 4 + 3] >> 1) + HALFG;
    int code = b * SXYZc + x * SYZc + y * SZc + z;
    unsigned h = hash32(code);
    while (true) {
        int old = atomicCAS(&tabB[h].x, -1, code);
        if (old == -1) { tabB[h].y = i; break; }
        if (old == code) break;   // duplicate (shouldn't occur)
        h = (h + 1) & TMASK;
    }
}

// ---- voxelize grid points, insert into dedupe hash, remember slot ----
__global__ void k_insertA(const float* __restrict__ gp, int2* tabA, int* slotA, int N) {
    int i = blockIdx.x * 256 + threadIdx.x;
    if (i >= N) return;
    float4 g = ((const float4*)gp)[i];
    int b = (int)g.x;
    int vx = (int)floorf(g.y / 0.08f); vx = min(max(vx, -(HALFG - 1)), HALFG - 1);
    int vy = (int)floorf(g.z / 0.08f); vy = min(max(vy, -(HALFG - 1)), HALFG - 1);
    int vz = (int)floorf(g.w / 0.08f); vz = min(max(vz, -(HALFG - 1)), HALFG - 1);
    int code = b * SXYZc + (vx + HALFG) * SYZc + (vy + HALFG) * SZc + (vz + HALFG);
    unsigned h = hash32(code);
    while (true) {
        int old = atomicCAS(&tabA[h].x, -1, code);
        if (old == -1 || old == code) break;
        h = (h + 1) & TMASK;
    }
    slotA[i] = (int)h;
}

// ---- assign unique ids by scanning hash slots ----
__global__ void k_assignUid(int2* tabA, int* __restrict__ ucode, int* nq) {
    int s = blockIdx.x * 256 + threadIdx.x;
    int c = tabA[s].x;
    if (c != -1) {
        int u = atomicAdd(nq, 1);
        tabA[s].y = u;
        ucode[u] = c;
    }
}

// ---- probe 125 offsets per unique voxel ----
__global__ void k_probe(const int* __restrict__ ucode, const int2* __restrict__ tabB,
                        int* hmark, int* cntk, int* bkUid, int* bkP,
                        const int* __restrict__ nqp, int N) {
    unsigned tid = blockIdx.x * 256u + threadIdx.x;
    if (tid >= (unsigned)N * KK) return;
    unsigned uid = tid / KK;
    if (uid >= (unsigned)(*nqp)) return;
    int k = (int)(tid - uid * KK);
    unsigned code = (unsigned)ucode[uid];
    unsigned b = code / SXYZc; unsigned rem = code - b * SXYZc;
    int x = (int)(rem / SYZc); rem -= (unsigned)x * SYZc;
    int y = (int)(rem / SZc);
    int z = (int)(rem - (unsigned)y * SZc);
    int q = k / 25; int r2 = k - q * 25;
    int dy = r2 / 5;
    x += q - 2; y += dy - 2; z += (r2 - dy * 5) - 2;
    if ((unsigned)x >= GG || (unsigned)y >= GG || (unsigned)z >= GG) return;
    int tcode = (int)b * SXYZc + x * SYZc + y * SZc + z;
    unsigned h = hash32(tcode);
    while (true) {
        int2 s = tabB[h];
        if (s.x == tcode) {
            hmark[uid] = 1;
            int pos = atomicAdd(&cntk[k], 1);
            if (pos < CAPK) { bkUid[k * CAPK + pos] = (int)uid; bkP[k * CAPK + pos] = s.y; }
            break;
        }
        if (s.x == -1) break;
        h = (h + 1) & TMASK;
    }
}

// ---- compact hit rows, zero their accumulators ----
__global__ void k_compact(const int* __restrict__ hmark, int* hidx, float* acc,
                          int* nh, const int* __restrict__ nqp) {
    int u = blockIdx.x * 256 + threadIdx.x;
    if (u >= *nqp) return;
    if (hmark[u]) {
        int hr = atomicAdd(nh, 1);
        hidx[u] = hr;
        float4* a4 = (float4*)(acc + (size_t)hr * CC);
        float4 z4 = make_float4(0.f, 0.f, 0.f, 0.f);
        #pragma unroll
        for (int c = 0; c < CC / 4; c++) a4[c] = z4;
    } else {
        hidx[u] = -1;
    }
}

// ---- sparse conv: hits grouped by kernel offset ----
__global__ __launch_bounds__(256) void k_conv(const float* __restrict__ spf,
        const float* __restrict__ W1, const int* __restrict__ cntk,
        const int* __restrict__ bkUid, const int* __restrict__ bkP,
        const int* __restrict__ hidx, float* acc) {
    int k = blockIdx.x;
    int cob = blockIdx.y * 64;
    int t = threadIdx.x;
    int co = cob + (t & 63);
    int lane = t >> 6;                  // 0..3, 8 rows each
    int cnt = min(cntk[k], CAPK);
    __shared__ float fs[32][CC];
    __shared__ int hrS[32];
    const float* Wk = W1 + (size_t)k * CC * CC;
    for (int tile = 0; tile < cnt; tile += 32) {
        int nt = min(32, cnt - tile);
        if (t < nt) hrS[t] = hidx[bkUid[k * CAPK + tile + t]];
        for (int e = t; e < 32 * CC; e += 256) {
            int r = e >> 7, c = e & 127;
            fs[r][c] = (r < nt) ? spf[(size_t)bkP[k * CAPK + tile + r] * CC + c] : 0.f;
        }
        __syncthreads();
        float a[8] = {0.f, 0.f, 0.f, 0.f, 0.f, 0.f, 0.f, 0.f};
        for (int ci = 0; ci < CC; ci++) {
            float w = Wk[(size_t)ci * CC + co];
            #pragma unroll
            for (int j = 0; j < 8; j++) a[j] += fs[lane * 8 + j][ci] * w;
        }
        #pragma unroll
        for (int j = 0; j < 8; j++) {
            int r = lane * 8 + j;
            if (r < nt) atomicAdd(&acc[(size_t)hrS[r] * CC + co], a[j]);
        }
        __syncthreads();
    }
}

// ---- BN1 stats over hit rows (zero rows contribute nothing) ----
__global__ void k_stats(const float* __restrict__ acc, float* gsum, float* gsumsq,
                        const int* __restrict__ nhp) {
    int t = threadIdx.x; int c = t & 127; int half = t >> 7;
    int nh = *nhp;
    float s = 0.f, s2 = 0.f;
    for (int r = blockIdx.x * 2 + half; r < nh; r += gridDim.x * 2) {
        float v = acc[(size_t)r * CC + c];
        s += v; s2 += v * v;
    }
    __shared__ float red[256];
    red[t] = s; __syncthreads();
    if (half == 0) atomicAdd(&gsum[c], s + red[t + 128]);
    __syncthreads();
    red[t] = s2; __syncthreads();
    if (half == 0) atomicAdd(&gsumsq[c], s2 + red[t + 128]);
}

// ---- Wsum = sum_p W2[p] ----
__global__ void k_wsum(const float* __restrict__ W2, float* Wsum) {
    int e = blockIdx.x * 256 + threadIdx.x;   // 0..16383
    int p0 = blockIdx.y * 49;
    float s = 0.f;
    for (int p = p0; p < p0 + 49; p++) s += W2[(size_t)p * (CC * CC) + e];
    atomicAdd(&Wsum[e], s);
}

// ---- mean/rs/c0 per channel + base = c0 @ Wsum ----
__global__ void k_bn1(const float* __restrict__ gsum, const float* __restrict__ gsumsq,
                      const float* __restrict__ g1, const float* __restrict__ b1,
                      const float* __restrict__ Wsum, float* meanv, float* rsv,
                      float* c0v, float* basev, const int* __restrict__ nqp) {
    int t = threadIdx.x;   // 128
    float n = (float)max(*nqp, 1);
    float mean = gsum[t] / n;
    float var = gsumsq[t] / n - mean * mean;
    float rs = 1.0f / sqrtf(var + EPSc);
    float c0 = (0.f - mean) * rs * g1[t] + b1[t];
    c0 = c0 > 0.f ? c0 : expm1f(c0);
    meanv[t] = mean; rsv[t] = rs; c0v[t] = c0;
    __shared__ float c0s[128];
    c0s[t] = c0; __syncthreads();
    float base = 0.f;
    for (int c = 0; c < 128; c++) base += c0s[c] * Wsum[c * 128 + t];
    basev[t] = base;
}

// ---- dx = elu(bn(acc)) - c0, in place on hit rows ----
__global__ void k_dx(float* acc, const float* __restrict__ meanv, const float* __restrict__ rsv,
                     const float* __restrict__ c0v, const float* __restrict__ g1,
                     const float* __restrict__ b1, const int* __restrict__ nhp) {
    int total = (*nhp) * CC;
    for (int e = blockIdx.x * 256 + threadIdx.x; e < total; e += gridDim.x * 256) {
        int c = e & 127;
        float v = acc[e];
        float x = (v - meanv[c]) * rsv[c] * g1[c] + b1[c];
        x = x > 0.f ? x : expm1f(x);
        acc[e] = x - c0v[c];
    }
}

// ---- pooled init: every roi row = base ----
__global__ void k_initpool(float* pooled, const float* __restrict__ basev, int NB) {
    int i = blockIdx.x * 256 + threadIdx.x;
    if (i < NB * CC) pooled[i] = basev[i & 127];
}

// ---- build sparse (b,p,hitrow) pairs bucketed by p ----
__global__ void k_pairs(const int* __restrict__ slotA, const int2* __restrict__ tabA,
                        const int* __restrict__ hidx, int* pcnt, int* pairPack, int N) {
    int i = blockIdx.x * 256 + threadIdx.x;
    if (i >= N) return;
    int uid = tabA[slotA[i]].y;
    int hr = hidx[uid];
    if (hr < 0) return;
    int b = i / PP;
    int p = i - b * PP;
    int pos = atomicAdd(&pcnt[p], 1);
    if (pos < CAPP) pairPack[p * CAPP + pos] = (b << 18) | hr;
}

// ---- sparse pooling: pairs grouped by p ----
__global__ __launch_bounds__(256) void k_pool(const float* __restrict__ acc,
        const float* __restrict__ W2, const int* __restrict__ pcnt,
        const int* __restrict__ pairPack, float* pooled) {
    int p = blockIdx.x;
    int cob = blockIdx.y * 64;
    int t = threadIdx.x;
    int co = cob + (t & 63);
    int lane = t >> 6;
    int cnt = min(pcnt[p], CAPP);
    __shared__ float fs[32][CC];
    __shared__ int bS[32];
    const float* Wp = W2 + (size_t)p * CC * CC;
    for (int tile = 0; tile < cnt; tile += 32) {
        int nt = min(32, cnt - tile);
        if (t < nt) bS[t] = pairPack[p * CAPP + tile + t] >> 18;
        for (int e = t; e < 32 * CC; e += 256) {
            int r = e >> 7, c = e & 127;
            float v = 0.f;
            if (r < nt) {
                int hr = pairPack[p * CAPP + tile + r] & 0x3FFFF;
                v = acc[(size_t)hr * CC + c];
            }
            fs[r][c] = v;
        }
        __syncthreads();
        float a[8] = {0.f, 0.f, 0.f, 0.f, 0.f, 0.f, 0.f, 0.f};
        for (int ci = 0; ci < CC; ci++) {
            float w = Wp[(size_t)ci * CC + co];
            #pragma unroll
            for (int j = 0; j < 8; j++) a[j] += fs[lane * 8 + j][ci] * w;
        }
        #pragma unroll
        for (int j = 0; j < 8; j++) {
            int r = lane * 8 + j;
            if (r < nt) atomicAdd(&pooled[(size_t)bS[r] * CC + co], a[j]);
        }
        __syncthreads();
    }
}

// ---- final BN over 512 rois ----
__global__ void k_bn2(const float* __restrict__ pooled, const float* __restrict__ g2,
                      const float* __restrict__ b2, float* out, int NB) {
    int d = blockIdx.x; int t = threadIdx.x;   // 64 threads = 1 wave
    float s = 0.f;
    for (int b = t; b < NB; b += 64) s += pooled[(size_t)b * CC + d];
    for (int o = 32; o >= 1; o >>= 1) s += __shfl_xor(s, o, 64);
    float mean = s / (float)NB;
    float s2 = 0.f;
    for (int b = t; b < NB; b += 64) { float v = pooled[(size_t)b * CC + d] - mean; s2 += v * v; }
    for (int o = 32; o >= 1; o >>= 1) s2 += __shfl_xor(s2, o, 64);
    float rs = 1.0f / sqrtf(s2 / (float)NB + EPSc);
    float gg = g2[d], bb = b2[d];
    for (int b = t; b < NB; b += 64)
        out[(size_t)b * CC + d] = (pooled[(size_t)b * CC + d] - mean) * rs * gg + bb;
}

extern "C" void kernel_launch(void* const* d_in, const int* in_sizes, int n_in,
                              void* d_out, int out_size, void* d_ws, size_t ws_size,
                              hipStream_t stream) {
    (void)n_in; (void)out_size; (void)ws_size;
    const int*   spc = (const int*)d_in[0];
    const float* spf = (const float*)d_in[1];
    const float* gp  = (const float*)d_in[2];
    const float* W1  = (const float*)d_in[3];
    const float* g1  = (const float*)d_in[4];
    const float* b1  = (const float*)d_in[5];
    const float* W2  = (const float*)d_in[6];
    const float* g2  = (const float*)d_in[7];
    const float* b2  = (const float*)d_in[8];
    int Nv = in_sizes[0] / 4;
    int N  = in_sizes[2] / 4;
    int NB = N / PP;
    float* out = (float*)d_out;

    char* w = (char*)d_ws;
    int2* tabA = (int2*)w; w += (size_t)TSLOTS * 8;
    int2* tabB = (int2*)w; w += (size_t)TSLOTS * 8;
    // ---- zero-init region (one memset) ----
    char* zero0 = w;
    int* nq   = (int*)w;          int* nh = nq + 1;  w += 64;
    int* cntk = (int*)w;          w += 128 * 4;
    int* pcnt = (int*)w;          w += 344 * 4;
    float* gsum   = (float*)w;    w += 128 * 4;
    float* gsumsq = (float*)w;    w += 128 * 4;
    float* Wsum   = (float*)w;    w += 16384 * 4;
    int* hmark    = (int*)w;      w += (size_t)N * 4;
    size_t zbytes = (size_t)(w - zero0);
    // ---- written-before-read region ----
    float* meanv = (float*)w;     w += 128 * 4;
    float* rsv   = (float*)w;     w += 128 * 4;
    float* c0v   = (float*)w;     w += 128 * 4;
    float* basev = (float*)w;     w += 128 * 4;
    int* ucode   = (int*)w;       w += (size_t)N * 4;
    int* slotA   = (int*)w;       w += (size_t)N * 4;
    int* hidx    = (int*)w;       w += (size_t)N * 4;
    int* bkUid   = (int*)w;       w += (size_t)KK * CAPK * 4;
    int* bkP     = (int*)w;       w += (size_t)KK * CAPK * 4;
    int* pairPack= (int*)w;       w += (size_t)PP * CAPP * 4;
    float* pooled= (float*)w;     w += (size_t)NB * CC * 4;
    float* acc   = (float*)w;     w += (size_t)N * CC * 4;

    hipMemsetAsync(tabA, 0xFF, (size_t)TSLOTS * 16, stream);  // tabA + tabB
    hipMemsetAsync(zero0, 0, zbytes, stream);

    k_buildB <<<(Nv + 255) / 256, 256, 0, stream>>>(spc, tabB, Nv);
    k_insertA<<<(N + 255) / 256, 256, 0, stream>>>(gp, tabA, slotA, N);
    k_assignUid<<<TSLOTS / 256, 256, 0, stream>>>(tabA, ucode, nq);
    long tot = (long)N * KK;
    k_probe  <<<(unsigned)((tot + 255) / 256), 256, 0, stream>>>(ucode, tabB, hmark, cntk,
                                                                 bkUid, bkP, nq, N);
    k_compact<<<(N + 255) / 256, 256, 0, stream>>>(hmark, hidx, acc, nh, nq);
    k_conv   <<<dim3(KK, 2), 256, 0, stream>>>(spf, W1, cntk, bkUid, bkP, hidx, acc);
    k_stats  <<<256, 256, 0, stream>>>(acc, gsum, gsumsq, nh);
    k_wsum   <<<dim3(64, 7), 256, 0, stream>>>(W2, Wsum);
    k_bn1    <<<1, 128, 0, stream>>>(gsum, gsumsq, g1, b1, Wsum, meanv, rsv, c0v, basev, nq);
    k_dx     <<<1024, 256, 0, stream>>>(acc, meanv, rsv, c0v, g1, b1, nh);
    k_initpool<<<(NB * CC + 255) / 256, 256, 0, stream>>>(pooled, basev, NB);
    k_pairs  <<<(N + 255) / 256, 256, 0, stream>>>(slotA, tabA, hidx, pcnt, pairPack, N);
    k_pool   <<<dim3(PP, 2), 256, 0, stream>>>(acc, W2, pcnt, pairPack, pooled);
    k_bn2    <<<CC, 64, 0, stream>>>(pooled, g2, b2, out, NB);
}

// Round 2
// 630.322 us; speedup vs baseline: 1.2538x; 1.2538x over previous
//
#include <hip/hip_runtime.h>
#include <math.h>

#define GG     384
#define HALFG  192
#define SZc    384
#define SYZc   147456
#define SXYZc  56623104
#define CC     128
#define PP     343
#define KK     125
// tabB: u32 tag-table, 2^20 slots = 4 MB (L2-resident per XCD)
#define TBBITS 20
#define TBSLOTS (1 << TBBITS)
#define TBMASK  (TBSLOTS - 1)
#define EMPTYB  0xFFFFFFFFu
// tabA: int2 dedupe table, 2^19 slots = 4 MB
#define TABITS 19
#define TASLOTS (1 << TABITS)
#define TAMASK  (TASLOTS - 1)
#define CAPK   2048
#define CAPP   1024
#define EPSc   1e-5f

__device__ __forceinline__ unsigned hash32(int code) {
    unsigned h = (unsigned)code;
    h ^= h >> 16; h *= 0x7feb352du;
    h ^= h >> 15; h *= 0x846ca68bu;
    h ^= h >> 16;
    return h;
}

// ---- build sp-voxel tag table: slot -> (tag14 | row18) ----
__global__ void k_buildB(const int4* __restrict__ spc4, unsigned* tabB, int Nv) {
    int i = blockIdx.x * 256 + threadIdx.x;
    if (i >= Nv) return;
    int4 s = spc4[i];
    int code = s.x * SXYZc + ((s.y >> 1) + HALFG) * SYZc
             + ((s.z >> 1) + HALFG) * SZc + ((s.w >> 1) + HALFG);
    unsigned h = hash32(code);
    unsigned slot = h & TBMASK;
    unsigned val = ((h >> 18) << 18) | (unsigned)i;   // tag | row
    while (true) {
        unsigned old = atomicCAS(&tabB[slot], EMPTYB, val);
        if (old == EMPTYB) break;
        slot = (slot + 1) & TBMASK;
    }
}

// ---- voxelize grid points, insert into dedupe hash, remember slot ----
__global__ void k_insertA(const float* __restrict__ gp, int2* tabA, int* slotA, int N) {
    int i = blockIdx.x * 256 + threadIdx.x;
    if (i >= N) return;
    float4 g = ((const float4*)gp)[i];
    int b = (int)g.x;
    int vx = (int)floorf(g.y / 0.08f); vx = min(max(vx, -(HALFG - 1)), HALFG - 1);
    int vy = (int)floorf(g.z / 0.08f); vy = min(max(vy, -(HALFG - 1)), HALFG - 1);
    int vz = (int)floorf(g.w / 0.08f); vz = min(max(vz, -(HALFG - 1)), HALFG - 1);
    int code = b * SXYZc + (vx + HALFG) * SYZc + (vy + HALFG) * SZc + (vz + HALFG);
    unsigned h = hash32(code) & TAMASK;
    while (true) {
        int old = atomicCAS(&tabA[h].x, -1, code);
        if (old == -1 || old == code) break;
        h = (h + 1) & TAMASK;
    }
    slotA[i] = (int)h;
}

// ---- assign unique ids (wave-aggregated atomic) ----
__global__ void k_assignUid(int2* tabA, int* __restrict__ ucode, int* nq) {
    int s = blockIdx.x * 256 + threadIdx.x;
    int c = tabA[s].x;
    bool occ = (c != -1);
    unsigned long long m = __ballot(occ);
    if (m == 0ull) return;
    int lane = threadIdx.x & 63;
    int leader = __ffsll((unsigned long long)m) - 1;
    int base = 0;
    if (lane == leader) base = atomicAdd(nq, __popcll(m));
    base = __shfl(base, leader, 64);
    if (occ) {
        int u = base + __popcll(m & ((1ull << lane) - 1ull));
        tabA[s].y = u;
        ucode[u] = c;
    }
}

// ---- probe 125 offsets per unique voxel against the L2-resident tag table ----
__global__ void k_probe(const int* __restrict__ ucode, const unsigned* __restrict__ tabB,
                        const int4* __restrict__ spc4,
                        int* hmark, int* cntk, int* bkUid, int* bkP,
                        const int* __restrict__ nqp, int N) {
    unsigned tid = blockIdx.x * 256u + threadIdx.x;
    if (tid >= (unsigned)N * KK) return;
    unsigned uid = tid / KK;
    if (uid >= (unsigned)(*nqp)) return;
    int k = (int)(tid - uid * KK);
    unsigned code = (unsigned)ucode[uid];
    unsigned b = code / SXYZc; unsigned rem = code - b * SXYZc;
    int x = (int)(rem / SYZc); rem -= (unsigned)x * SYZc;
    int y = (int)(rem / SZc);
    int z = (int)(rem - (unsigned)y * SZc);
    int q = k / 25; int r2 = k - q * 25;
    int dy = r2 / 5;
    x += q - 2; y += dy - 2; z += (r2 - dy * 5) - 2;
    if ((unsigned)x >= GG || (unsigned)y >= GG || (unsigned)z >= GG) return;
    int tcode = (int)b * SXYZc + x * SYZc + y * SZc + z;
    unsigned h = hash32(tcode);
    unsigned slot = h & TBMASK;
    unsigned tag = h >> 18;
    while (true) {
        unsigned v = tabB[slot];
        if (v == EMPTYB) return;                 // definite miss
        if ((v >> 18) == tag) {
            int row = (int)(v & 0x3FFFFu);
            int4 s = spc4[row];                  // exact verification
            int rcode = s.x * SXYZc + ((s.y >> 1) + HALFG) * SYZc
                      + ((s.z >> 1) + HALFG) * SZc + ((s.w >> 1) + HALFG);
            if (rcode == tcode) {
                hmark[uid] = 1;
                int pos = atomicAdd(&cntk[k], 1);
                if (pos < CAPK) { bkUid[k * CAPK + pos] = (int)uid; bkP[k * CAPK + pos] = row; }
                return;
            }
        }
        slot = (slot + 1) & TBMASK;
    }
}

// ---- compact hit rows (wave-aggregated), zero their accumulators ----
__global__ void k_compact(const int* __restrict__ hmark, int* hidx, float* acc,
                          int* nh, const int* __restrict__ nqp) {
    int u = blockIdx.x * 256 + threadIdx.x;
    bool hit = (u < *nqp) && hmark[u];
    unsigned long long m = __ballot(hit);
    if (u >= *nqp && m == 0ull) { if (u < (blockIdx.x + 1) * 256) ; }
    int lane = threadIdx.x & 63;
    int hr = -1;
    if (m != 0ull) {
        int leader = __ffsll((unsigned long long)m) - 1;
        int base = 0;
        if (lane == leader) base = atomicAdd(nh, __popcll(m));
        base = __shfl(base, leader, 64);
        if (hit) hr = base + __popcll(m & ((1ull << lane) - 1ull));
    }
    if (u < *nqp) hidx[u] = hr;
    if (hr >= 0) {
        float4* a4 = (float4*)(acc + (size_t)hr * CC);
        float4 z4 = make_float4(0.f, 0.f, 0.f, 0.f);
        #pragma unroll
        for (int c = 0; c < CC / 4; c++) a4[c] = z4;
    }
}

// ---- sparse conv: hits grouped by kernel offset ----
__global__ __launch_bounds__(256) void k_conv(const float* __restrict__ spf,
        const float* __restrict__ W1, const int* __restrict__ cntk,
        const int* __restrict__ bkUid, const int* __restrict__ bkP,
        const int* __restrict__ hidx, float* acc) {
    int k = blockIdx.x;
    int cob = blockIdx.y * 64;
    int t = threadIdx.x;
    int co = cob + (t & 63);
    int lane = t >> 6;                  // 0..3, 8 rows each
    int cnt = min(cntk[k], CAPK);
    __shared__ float fs[32][CC];
    __shared__ int hrS[32];
    const float* Wk = W1 + (size_t)k * CC * CC;
    for (int tile = 0; tile < cnt; tile += 32) {
        int nt = min(32, cnt - tile);
        if (t < nt) hrS[t] = hidx[bkUid[k * CAPK + tile + t]];
        for (int e = t; e < 32 * CC; e += 256) {
            int r = e >> 7, c = e & 127;
            fs[r][c] = (r < nt) ? spf[(size_t)bkP[k * CAPK + tile + r] * CC + c] : 0.f;
        }
        __syncthreads();
        float a[8] = {0.f, 0.f, 0.f, 0.f, 0.f, 0.f, 0.f, 0.f};
        for (int ci = 0; ci < CC; ci++) {
            float w = Wk[(size_t)ci * CC + co];
            #pragma unroll
            for (int j = 0; j < 8; j++) a[j] += fs[lane * 8 + j][ci] * w;
        }
        #pragma unroll
        for (int j = 0; j < 8; j++) {
            int r = lane * 8 + j;
            if (r < nt) atomicAdd(&acc[(size_t)hrS[r] * CC + co], a[j]);
        }
        __syncthreads();
    }
}

// ---- BN1 stats over hit rows (zero rows contribute nothing) ----
__global__ void k_stats(const float* __restrict__ acc, float* gsum, float* gsumsq,
                        const int* __restrict__ nhp) {
    int t = threadIdx.x; int c = t & 127; int half = t >> 7;
    int nh = *nhp;
    float s = 0.f, s2 = 0.f;
    for (int r = blockIdx.x * 2 + half; r < nh; r += gridDim.x * 2) {
        float v = acc[(size_t)r * CC + c];
        s += v; s2 += v * v;
    }
    __shared__ float red[256];
    red[t] = s; __syncthreads();
    if (half == 0) atomicAdd(&gsum[c], s + red[t + 128]);
    __syncthreads();
    red[t] = s2; __syncthreads();
    if (half == 0) atomicAdd(&gsumsq[c], s2 + red[t + 128]);
}

// ---- Wsum = sum_p W2[p] ----
__global__ void k_wsum(const float* __restrict__ W2, float* Wsum) {
    int e = blockIdx.x * 256 + threadIdx.x;   // 0..16383
    int p0 = blockIdx.y * 49;
    float s = 0.f;
    for (int p = p0; p < p0 + 49; p++) s += W2[(size_t)p * (CC * CC) + e];
    atomicAdd(&Wsum[e], s);
}

// ---- mean/rs/c0 per channel + base = c0 @ Wsum ----
__global__ void k_bn1(const float* __restrict__ gsum, const float* __restrict__ gsumsq,
                      const float* __restrict__ g1, const float* __restrict__ b1,
                      const float* __restrict__ Wsum, float* meanv, float* rsv,
                      float* c0v, float* basev, const int* __restrict__ nqp) {
    int t = threadIdx.x;   // 128
    float n = (float)max(*nqp, 1);
    float mean = gsum[t] / n;
    float var = gsumsq[t] / n - mean * mean;
    float rs = 1.0f / sqrtf(var + EPSc);
    float c0 = (0.f - mean) * rs * g1[t] + b1[t];
    c0 = c0 > 0.f ? c0 : expm1f(c0);
    meanv[t] = mean; rsv[t] = rs; c0v[t] = c0;
    __shared__ float c0s[128];
    c0s[t] = c0; __syncthreads();
    float base = 0.f;
    for (int c = 0; c < 128; c++) base += c0s[c] * Wsum[c * 128 + t];
    basev[t] = base;
}

// ---- dx = elu(bn(acc)) - c0, in place on hit rows ----
__global__ void k_dx(float* acc, const float* __restrict__ meanv, const float* __restrict__ rsv,
                     const float* __restrict__ c0v, const float* __restrict__ g1,
                     const float* __restrict__ b1, const int* __restrict__ nhp) {
    int total = (*nhp) * CC;
    for (int e = blockIdx.x * 256 + threadIdx.x; e < total; e += gridDim.x * 256) {
        int c = e & 127;
        float v = acc[e];
        float x = (v - meanv[c]) * rsv[c] * g1[c] + b1[c];
        x = x > 0.f ? x : expm1f(x);
        acc[e] = x - c0v[c];
    }
}

// ---- pooled init: every roi row = base ----
__global__ void k_initpool(float* pooled, const float* __restrict__ basev, int NB) {
    int i = blockIdx.x * 256 + threadIdx.x;
    if (i < NB * CC) pooled[i] = basev[i & 127];
}

// ---- build sparse (b,p,hitrow) pairs bucketed by p ----
__global__ void k_pairs(const int* __restrict__ slotA, const int2* __restrict__ tabA,
                        const int* __restrict__ hidx, int* pcnt, int* pairPack, int N) {
    int i = blockIdx.x * 256 + threadIdx.x;
    if (i >= N) return;
    int uid = tabA[slotA[i]].y;
    int hr = hidx[uid];
    if (hr < 0) return;
    int b = i / PP;
    int p = i - b * PP;
    int pos = atomicAdd(&pcnt[p], 1);
    if (pos < CAPP) pairPack[p * CAPP + pos] = (b << 18) | hr;
}

// ---- sparse pooling: pairs grouped by p ----
__global__ __launch_bounds__(256) void k_pool(const float* __restrict__ acc,
        const float* __restrict__ W2, const int* __restrict__ pcnt,
        const int* __restrict__ pairPack, float* pooled) {
    int p = blockIdx.x;
    int cob = blockIdx.y * 64;
    int t = threadIdx.x;
    int co = cob + (t & 63);
    int lane = t >> 6;
    int cnt = min(pcnt[p], CAPP);
    __shared__ float fs[32][CC];
    __shared__ int bS[32];
    const float* Wp = W2 + (size_t)p * CC * CC;
    for (int tile = 0; tile < cnt; tile += 32) {
        int nt = min(32, cnt - tile);
        if (t < nt) bS[t] = pairPack[p * CAPP + tile + t] >> 18;
        for (int e = t; e < 32 * CC; e += 256) {
            int r = e >> 7, c = e & 127;
            float v = 0.f;
            if (r < nt) {
                int hr = pairPack[p * CAPP + tile + r] & 0x3FFFF;
                v = acc[(size_t)hr * CC + c];
            }
            fs[r][c] = v;
        }
        __syncthreads();
        float a[8] = {0.f, 0.f, 0.f, 0.f, 0.f, 0.f, 0.f, 0.f};
        for (int ci = 0; ci < CC; ci++) {
            float w = Wp[(size_t)ci * CC + co];
            #pragma unroll
            for (int j = 0; j < 8; j++) a[j] += fs[lane * 8 + j][ci] * w;
        }
        #pragma unroll
        for (int j = 0; j < 8; j++) {
            int r = lane * 8 + j;
            if (r < nt) atomicAdd(&pooled[(size_t)bS[r] * CC + co], a[j]);
        }
        __syncthreads();
    }
}

// ---- final BN over 512 rois ----
__global__ void k_bn2(const float* __restrict__ pooled, const float* __restrict__ g2,
                      const float* __restrict__ b2, float* out, int NB) {
    int d = blockIdx.x; int t = threadIdx.x;   // 64 threads = 1 wave
    float s = 0.f;
    for (int b = t; b < NB; b += 64) s += pooled[(size_t)b * CC + d];
    for (int o = 32; o >= 1; o >>= 1) s += __shfl_xor(s, o, 64);
    float mean = s / (float)NB;
    float s2 = 0.f;
    for (int b = t; b < NB; b += 64) { float v = pooled[(size_t)b * CC + d] - mean; s2 += v * v; }
    for (int o = 32; o >= 1; o >>= 1) s2 += __shfl_xor(s2, o, 64);
    float rs = 1.0f / sqrtf(s2 / (float)NB + EPSc);
    float gg = g2[d], bb = b2[d];
    for (int b = t; b < NB; b += 64)
        out[(size_t)b * CC + d] = (pooled[(size_t)b * CC + d] - mean) * rs * gg + bb;
}

extern "C" void kernel_launch(void* const* d_in, const int* in_sizes, int n_in,
                              void* d_out, int out_size, void* d_ws, size_t ws_size,
                              hipStream_t stream) {
    (void)n_in; (void)out_size; (void)ws_size;
    const int*   spc = (const int*)d_in[0];
    const float* spf = (const float*)d_in[1];
    const float* gp  = (const float*)d_in[2];
    const float* W1  = (const float*)d_in[3];
    const float* g1  = (const float*)d_in[4];
    const float* b1  = (const float*)d_in[5];
    const float* W2  = (const float*)d_in[6];
    const float* g2  = (const float*)d_in[7];
    const float* b2  = (const float*)d_in[8];
    int Nv = in_sizes[0] / 4;
    int N  = in_sizes[2] / 4;
    int NB = N / PP;
    float* out = (float*)d_out;

    char* w = (char*)d_ws;
    unsigned* tabB = (unsigned*)w; w += (size_t)TBSLOTS * 4;   // 4 MB
    int2*     tabA = (int2*)w;     w += (size_t)TASLOTS * 8;   // 4 MB (adjacent: one 0xFF memset)
    // ---- zero-init region (one memset) ----
    char* zero0 = w;
    int* nq   = (int*)w;          int* nh = nq + 1;  w += 64;
    int* cntk = (int*)w;          w += 128 * 4;
    int* pcnt = (int*)w;          w += 344 * 4;
    float* gsum   = (float*)w;    w += 128 * 4;
    float* gsumsq = (float*)w;    w += 128 * 4;
    float* Wsum   = (float*)w;    w += 16384 * 4;
    int* hmark    = (int*)w;      w += (size_t)N * 4;
    size_t zbytes = (size_t)(w - zero0);
    // ---- written-before-read region ----
    float* meanv = (float*)w;     w += 128 * 4;
    float* rsv   = (float*)w;     w += 128 * 4;
    float* c0v   = (float*)w;     w += 128 * 4;
    float* basev = (float*)w;     w += 128 * 4;
    int* ucode   = (int*)w;       w += (size_t)N * 4;
    int* slotA   = (int*)w;       w += (size_t)N * 4;
    int* hidx    = (int*)w;       w += (size_t)N * 4;
    int* bkUid   = (int*)w;       w += (size_t)KK * CAPK * 4;
    int* bkP     = (int*)w;       w += (size_t)KK * CAPK * 4;
    int* pairPack= (int*)w;       w += (size_t)PP * CAPP * 4;
    float* pooled= (float*)w;     w += (size_t)NB * CC * 4;
    float* acc   = (float*)w;     w += (size_t)N * CC * 4;

    hipMemsetAsync(tabB, 0xFF, (size_t)TBSLOTS * 4 + (size_t)TASLOTS * 8, stream);
    hipMemsetAsync(zero0, 0, zbytes, stream);

    k_buildB <<<(Nv + 255) / 256, 256, 0, stream>>>((const int4*)spc, tabB, Nv);
    k_insertA<<<(N + 255) / 256, 256, 0, stream>>>(gp, tabA, slotA, N);
    k_assignUid<<<TASLOTS / 256, 256, 0, stream>>>(tabA, ucode, nq);
    long tot = (long)N * KK;
    k_probe  <<<(unsigned)((tot + 255) / 256), 256, 0, stream>>>(ucode, tabB, (const int4*)spc,
                                                                 hmark, cntk, bkUid, bkP, nq, N);
    k_compact<<<(N + 255) / 256, 256, 0, stream>>>(hmark, hidx, acc, nh, nq);
    k_conv   <<<dim3(KK, 2), 256, 0, stream>>>(spf, W1, cntk, bkUid, bkP, hidx, acc);
    k_stats  <<<256, 256, 0, stream>>>(acc, gsum, gsumsq, nh);
    k_wsum   <<<dim3(64, 7), 256, 0, stream>>>(W2, Wsum);
    k_bn1    <<<1, 128, 0, stream>>>(gsum, gsumsq, g1, b1, Wsum, meanv, rsv, c0v, basev, nq);
    k_dx     <<<1024, 256, 0, stream>>>(acc, meanv, rsv, c0v, g1, b1, nh);
    k_initpool<<<(NB * CC + 255) / 256, 256, 0, stream>>>(pooled, basev, NB);
    k_pairs  <<<(N + 255) / 256, 256, 0, stream>>>(slotA, tabA, hidx, pcnt, pairPack, N);
    k_pool   <<<dim3(PP, 2), 256, 0, stream>>>(acc, W2, pcnt, pairPack, pooled);
    k_bn2    <<<CC, 64, 0, stream>>>(pooled, g2, b2, out, NB);
}

// Round 3
// 544.053 us; speedup vs baseline: 1.4527x; 1.1586x over previous
//
#include <hip/hip_runtime.h>
#include <math.h>

#define GG     384
#define HALFG  192
#define SZc    384
#define SYZc   147456
#define SXYZc  56623104
#define CC     128
#define PP     343
#define KK     125
// tabB: u32 tag-table for sp voxels, 2^20 slots = 4 MB
#define TBBITS 20
#define TBSLOTS (1 << TBBITS)
#define TBMASK  (TBSLOTS - 1)
#define EMPTYB  0xFFFFFFFFu
// colKV: u64 exact hash (b,x,y)->cid, 2^19 slots = 4 MB
#define CHBITS 19
#define CHSLOTS (1 << CHBITS)
#define CHMASK  (CHSLOTS - 1)
#define EMPTYC  0xFFFFFFFFFFFFFFFFull
#define MAXCOL  (1 << 18)
// tabA: int2 dedupe table for grid voxels, 2^19 slots = 4 MB
#define TABITS 19
#define TASLOTS (1 << TABITS)
#define TAMASK  (TASLOTS - 1)
#define CAPK   2048
#define CAPP   1024
#define EPSc   1e-5f

typedef unsigned long long u64;

__device__ __forceinline__ unsigned hash32(int code) {
    unsigned h = (unsigned)code;
    h ^= h >> 16; h *= 0x7feb352du;
    h ^= h >> 15; h *= 0x846ca68bu;
    h ^= h >> 16;
    return h;
}

// ---- build: sp-voxel tag table + column hash + column z-bitmaps ----
__global__ void k_build(const int4* __restrict__ spc4, unsigned* tabB,
                        u64* colKV, u64* colBM, int* ncol, int Nv) {
    int i = blockIdx.x * 256 + threadIdx.x;
    if (i >= Nv) return;
    int4 s = spc4[i];
    int b = s.x;
    int x = (s.y >> 1) + HALFG;
    int y = (s.z >> 1) + HALFG;
    int z = (s.w >> 1) + HALFG;
    int code = b * SXYZc + x * SYZc + y * SZc + z;
    // 1) exact-row tag table
    unsigned h = hash32(code);
    unsigned slot = h & TBMASK;
    unsigned val = ((h >> 18) << 18) | (unsigned)i;
    while (true) {
        unsigned old = atomicCAS(&tabB[slot], EMPTYB, val);
        if (old == EMPTYB) break;
        slot = (slot + 1) & TBMASK;
    }
    // 2) column hash + bitmap
    int ccode = (b * GG + x) * GG + y;           // < 2^20
    int cid = atomicAdd(ncol, 1);                // optimistic alloc (burn ok, Nv < MAXCOL)
    u64 ent = ((u64)(unsigned)ccode << 18) | (unsigned)cid;
    unsigned cs = hash32(ccode) & CHMASK;
    while (true) {
        u64 old = atomicCAS(&colKV[cs], EMPTYC, ent);
        if (old == EMPTYC) break;
        if ((old >> 18) == (u64)(unsigned)ccode) { cid = (int)(old & 0x3FFFFull); break; }
        cs = (cs + 1) & CHMASK;
    }
    atomicOr(&colBM[(size_t)cid * 6 + (z >> 6)], 1ull << (z & 63));
}

// ---- voxelize grid points, insert into dedupe hash, remember slot ----
__global__ void k_insertA(const float* __restrict__ gp, int2* tabA, int* slotA, int N) {
    int i = blockIdx.x * 256 + threadIdx.x;
    if (i >= N) return;
    float4 g = ((const float4*)gp)[i];
    int b = (int)g.x;
    int vx = (int)floorf(g.y / 0.08f); vx = min(max(vx, -(HALFG - 1)), HALFG - 1);
    int vy = (int)floorf(g.z / 0.08f); vy = min(max(vy, -(HALFG - 1)), HALFG - 1);
    int vz = (int)floorf(g.w / 0.08f); vz = min(max(vz, -(HALFG - 1)), HALFG - 1);
    int code = b * SXYZc + (vx + HALFG) * SYZc + (vy + HALFG) * SZc + (vz + HALFG);
    unsigned h = hash32(code) & TAMASK;
    while (true) {
        int old = atomicCAS(&tabA[h].x, -1, code);
        if (old == -1 || old == code) break;
        h = (h + 1) & TAMASK;
    }
    slotA[i] = (int)h;
}

// ---- assign unique ids (wave-aggregated atomic) ----
__global__ void k_assignUid(int2* tabA, int* __restrict__ ucode, int* nq) {
    int s = blockIdx.x * 256 + threadIdx.x;
    int c = tabA[s].x;
    bool occ = (c != -1);
    unsigned long long m = __ballot(occ);
    if (m == 0ull) return;
    int lane = threadIdx.x & 63;
    int leader = __ffsll(m) - 1;
    int base = 0;
    if (lane == leader) base = atomicAdd(nq, __popcll(m));
    base = __shfl(base, leader, 64);
    if (occ) {
        int u = base + __popcll(m & ((1ull << lane) - 1ull));
        tabA[s].y = u;
        ucode[u] = c;
    }
}

// ---- probe: 25 columns per uid, 5-bit z-window from bitmap, exact resolve on hit ----
__global__ void k_probe(const int* __restrict__ ucode, const u64* __restrict__ colKV,
                        const u64* __restrict__ colBM, const unsigned* __restrict__ tabB,
                        const int4* __restrict__ spc4,
                        int* hmark, int* cntk, int* bkUid, int* bkP,
                        const int* __restrict__ nqp, int N) {
    unsigned tid = blockIdx.x * 256u + threadIdx.x;
    if (tid >= (unsigned)N * 25u) return;
    unsigned uid = tid / 25u;
    if (uid >= (unsigned)(*nqp)) return;
    int c = (int)(tid - uid * 25u);      // c = dx*5 + dy
    unsigned code = (unsigned)ucode[uid];
    unsigned b = code / SXYZc; unsigned rem = code - b * SXYZc;
    int x = (int)(rem / SYZc); rem -= (unsigned)x * SYZc;
    int y = (int)(rem / SZc);
    int z = (int)(rem - (unsigned)y * SZc);
    int dx = c / 5, dy = c - dx * 5;
    int cx = x + dx - 2, cy = y + dy - 2;
    if ((unsigned)cx >= GG || (unsigned)cy >= GG) return;
    int ccode = ((int)b * GG + cx) * GG + cy;
    unsigned cs = hash32(ccode) & CHMASK;
    int cid = -1;
    while (true) {
        u64 e = colKV[cs];
        if (e == EMPTYC) return;                       // column unoccupied
        if ((e >> 18) == (u64)(unsigned)ccode) { cid = (int)(e & 0x3FFFFull); break; }
        cs = (cs + 1) & CHMASK;
    }
    int lo = max(z - 2, 0);
    int hi = min(z + 2, GG - 1);
    int width = hi - lo + 1;
    int i0 = lo >> 6, sh = lo & 63;
    const u64* bm = colBM + (size_t)cid * 6;
    u64 w = bm[i0] >> sh;
    if (sh + width > 64) w |= bm[i0 + 1] << (64 - sh);
    unsigned bits = (unsigned)(w & ((1ull << width) - 1ull));
    if (bits == 0) return;
    hmark[uid] = 1;
    int zbase = z - 2;
    while (bits) {
        int j = __builtin_ctz(bits);
        bits &= bits - 1;
        int tz = lo + j;
        int dz = tz - zbase;                           // 0..4
        int k = c * 5 + dz;
        int tcode = (int)b * SXYZc + cx * SYZc + cy * SZc + tz;
        // exact row resolution via tag table
        unsigned h = hash32(tcode);
        unsigned slot = h & TBMASK;
        unsigned tag = h >> 18;
        while (true) {
            unsigned v = tabB[slot];
            if (v == EMPTYB) break;                    // shouldn't happen
            if ((v >> 18) == tag) {
                int row = (int)(v & 0x3FFFFu);
                int4 s = spc4[row];
                int rcode = s.x * SXYZc + ((s.y >> 1) + HALFG) * SYZc
                          + ((s.z >> 1) + HALFG) * SZc + ((s.w >> 1) + HALFG);
                if (rcode == tcode) {
                    int pos = atomicAdd(&cntk[k], 1);
                    if (pos < CAPK) { bkUid[k * CAPK + pos] = (int)uid; bkP[k * CAPK + pos] = row; }
                    break;
                }
            }
            slot = (slot + 1) & TBMASK;
        }
    }
}

// ---- compact hit rows (wave-aggregated), zero their accumulators ----
__global__ void k_compact(const int* __restrict__ hmark, int* hidx, float* acc,
                          int* nh, const int* __restrict__ nqp) {
    int u = blockIdx.x * 256 + threadIdx.x;
    bool hit = (u < *nqp) && hmark[u];
    unsigned long long m = __ballot(hit);
    int lane = threadIdx.x & 63;
    int hr = -1;
    if (m != 0ull) {
        int leader = __ffsll(m) - 1;
        int base = 0;
        if (lane == leader) base = atomicAdd(nh, __popcll(m));
        base = __shfl(base, leader, 64);
        if (hit) hr = base + __popcll(m & ((1ull << lane) - 1ull));
    }
    if (u < *nqp) hidx[u] = hr;
    if (hr >= 0) {
        float4* a4 = (float4*)(acc + (size_t)hr * CC);
        float4 z4 = make_float4(0.f, 0.f, 0.f, 0.f);
        #pragma unroll
        for (int cc = 0; cc < CC / 4; cc++) a4[cc] = z4;
    }
}

// ---- sparse conv: hits grouped by kernel offset, tile-strided over grid.z ----
__global__ __launch_bounds__(256) void k_conv(const float* __restrict__ spf,
        const float* __restrict__ W1, const int* __restrict__ cntk,
        const int* __restrict__ bkUid, const int* __restrict__ bkP,
        const int* __restrict__ hidx, float* acc) {
    int k = blockIdx.x;
    int cob = blockIdx.y * 64;
    int t = threadIdx.x;
    int co = cob + (t & 63);
    int lane = t >> 6;                  // 0..3, 8 rows each
    int cnt = min(cntk[k], CAPK);
    __shared__ float fs[32][CC];
    __shared__ int hrS[32];
    const float* Wk = W1 + (size_t)k * CC * CC;
    for (int tile = blockIdx.z * 32; tile < cnt; tile += 32 * gridDim.z) {
        int nt = min(32, cnt - tile);
        if (t < nt) hrS[t] = hidx[bkUid[k * CAPK + tile + t]];
        for (int e = t; e < 32 * CC; e += 256) {
            int r = e >> 7, cc = e & 127;
            fs[r][cc] = (r < nt) ? spf[(size_t)bkP[k * CAPK + tile + r] * CC + cc] : 0.f;
        }
        __syncthreads();
        float a[8] = {0.f, 0.f, 0.f, 0.f, 0.f, 0.f, 0.f, 0.f};
        for (int ci = 0; ci < CC; ci++) {
            float wv = Wk[(size_t)ci * CC + co];
            #pragma unroll
            for (int j = 0; j < 8; j++) a[j] += fs[lane * 8 + j][ci] * wv;
        }
        #pragma unroll
        for (int j = 0; j < 8; j++) {
            int r = lane * 8 + j;
            if (r < nt) atomicAdd(&acc[(size_t)hrS[r] * CC + co], a[j]);
        }
        __syncthreads();
    }
}

// ---- BN1 stats over hit rows (zero rows contribute nothing) ----
__global__ void k_stats(const float* __restrict__ acc, float* gsum, float* gsumsq,
                        const int* __restrict__ nhp) {
    int t = threadIdx.x; int c = t & 127; int half = t >> 7;
    int nh = *nhp;
    float s = 0.f, s2 = 0.f;
    for (int r = blockIdx.x * 2 + half; r < nh; r += gridDim.x * 2) {
        float v = acc[(size_t)r * CC + c];
        s += v; s2 += v * v;
    }
    __shared__ float red[256];
    red[t] = s; __syncthreads();
    if (half == 0) atomicAdd(&gsum[c], s + red[t + 128]);
    __syncthreads();
    red[t] = s2; __syncthreads();
    if (half == 0) atomicAdd(&gsumsq[c], s2 + red[t + 128]);
}

// ---- mean/rs/c0 per channel (base path eliminated: cancels in BN2) ----
__global__ void k_bn1(const float* __restrict__ gsum, const float* __restrict__ gsumsq,
                      const float* __restrict__ g1, const float* __restrict__ b1,
                      float* meanv, float* rsv, float* c0v, const int* __restrict__ nqp) {
    int t = threadIdx.x;   // 128
    float n = (float)max(*nqp, 1);
    float mean = gsum[t] / n;
    float var = gsumsq[t] / n - mean * mean;
    float rs = 1.0f / sqrtf(var + EPSc);
    float c0 = (0.f - mean) * rs * g1[t] + b1[t];
    c0 = c0 > 0.f ? c0 : expm1f(c0);
    meanv[t] = mean; rsv[t] = rs; c0v[t] = c0;
}

// ---- dx = elu(bn(acc)) - c0, in place on hit rows ----
__global__ void k_dx(float* acc, const float* __restrict__ meanv, const float* __restrict__ rsv,
                     const float* __restrict__ c0v, const float* __restrict__ g1,
                     const float* __restrict__ b1, const int* __restrict__ nhp) {
    int total = (*nhp) * CC;
    for (int e = blockIdx.x * 256 + threadIdx.x; e < total; e += gridDim.x * 256) {
        int c = e & 127;
        float v = acc[e];
        float x = (v - meanv[c]) * rsv[c] * g1[c] + b1[c];
        x = x > 0.f ? x : expm1f(x);
        acc[e] = x - c0v[c];
    }
}

// ---- build sparse (b,p,hitrow) pairs bucketed by p ----
__global__ void k_pairs(const int* __restrict__ slotA, const int2* __restrict__ tabA,
                        const int* __restrict__ hidx, int* pcnt, int* pairPack, int N) {
    int i = blockIdx.x * 256 + threadIdx.x;
    if (i >= N) return;
    int uid = tabA[slotA[i]].y;
    int hr = hidx[uid];
    if (hr < 0) return;
    int b = i / PP;
    int p = i - b * PP;
    int pos = atomicAdd(&pcnt[p], 1);
    if (pos < CAPP) pairPack[p * CAPP + pos] = (b << 18) | hr;
}

// ---- sparse pooling: pairs grouped by p (pooled starts at zero; base cancels) ----
__global__ __launch_bounds__(256) void k_pool(const float* __restrict__ acc,
        const float* __restrict__ W2, const int* __restrict__ pcnt,
        const int* __restrict__ pairPack, float* pooled) {
    int p = blockIdx.x;
    int cob = blockIdx.y * 64;
    int t = threadIdx.x;
    int co = cob + (t & 63);
    int lane = t >> 6;
    int cnt = min(pcnt[p], CAPP);
    __shared__ float fs[32][CC];
    __shared__ int bS[32];
    const float* Wp = W2 + (size_t)p * CC * CC;
    for (int tile = blockIdx.z * 32; tile < cnt; tile += 32 * gridDim.z) {
        int nt = min(32, cnt - tile);
        if (t < nt) bS[t] = pairPack[p * CAPP + tile + t] >> 18;
        for (int e = t; e < 32 * CC; e += 256) {
            int r = e >> 7, cc = e & 127;
            float v = 0.f;
            if (r < nt) {
                int hr = pairPack[p * CAPP + tile + r] & 0x3FFFF;
                v = acc[(size_t)hr * CC + cc];
            }
            fs[r][cc] = v;
        }
        __syncthreads();
        float a[8] = {0.f, 0.f, 0.f, 0.f, 0.f, 0.f, 0.f, 0.f};
        for (int ci = 0; ci < CC; ci++) {
            float wv = Wp[(size_t)ci * CC + co];
            #pragma unroll
            for (int j = 0; j < 8; j++) a[j] += fs[lane * 8 + j][ci] * wv;
        }
        #pragma unroll
        for (int j = 0; j < 8; j++) {
            int r = lane * 8 + j;
            if (r < nt) atomicAdd(&pooled[(size_t)bS[r] * CC + co], a[j]);
        }
        __syncthreads();
    }
}

// ---- final BN over 512 rois (operates on delta; constant base cancels) ----
__global__ void k_bn2(const float* __restrict__ pooled, const float* __restrict__ g2,
                      const float* __restrict__ b2, float* out, int NB) {
    int d = blockIdx.x; int t = threadIdx.x;   // 64 threads = 1 wave
    float s = 0.f;
    for (int b = t; b < NB; b += 64) s += pooled[(size_t)b * CC + d];
    for (int o = 32; o >= 1; o >>= 1) s += __shfl_xor(s, o, 64);
    float mean = s / (float)NB;
    float s2 = 0.f;
    for (int b = t; b < NB; b += 64) { float v = pooled[(size_t)b * CC + d] - mean; s2 += v * v; }
    for (int o = 32; o >= 1; o >>= 1) s2 += __shfl_xor(s2, o, 64);
    float rs = 1.0f / sqrtf(s2 / (float)NB + EPSc);
    float gg = g2[d], bb = b2[d];
    for (int b = t; b < NB; b += 64)
        out[(size_t)b * CC + d] = (pooled[(size_t)b * CC + d] - mean) * rs * gg + bb;
}

extern "C" void kernel_launch(void* const* d_in, const int* in_sizes, int n_in,
                              void* d_out, int out_size, void* d_ws, size_t ws_size,
                              hipStream_t stream) {
    (void)n_in; (void)out_size; (void)ws_size;
    const int*   spc = (const int*)d_in[0];
    const float* spf = (const float*)d_in[1];
    const float* gp  = (const float*)d_in[2];
    const float* W1  = (const float*)d_in[3];
    const float* g1  = (const float*)d_in[4];
    const float* b1  = (const float*)d_in[5];
    const float* W2  = (const float*)d_in[6];
    const float* g2  = (const float*)d_in[7];
    const float* b2  = (const float*)d_in[8];
    int Nv = in_sizes[0] / 4;
    int N  = in_sizes[2] / 4;
    int NB = N / PP;
    float* out = (float*)d_out;

    char* w = (char*)d_ws;
    // ---- 0xFF-init region (one memset) ----
    unsigned* tabB = (unsigned*)w; w += (size_t)TBSLOTS * 4;   // 4 MB
    u64*     colKV = (u64*)w;      w += (size_t)CHSLOTS * 8;   // 4 MB
    int2*     tabA = (int2*)w;     w += (size_t)TASLOTS * 8;   // 4 MB
    size_t ffbytes = (size_t)(w - (char*)d_ws);
    // ---- zero-init region (one memset) ----
    char* zero0 = w;
    int* nq   = (int*)w;  int* nh = nq + 1;  int* ncol = nq + 2;  w += 64;
    u64* colBM = (u64*)w;         w += (size_t)MAXCOL * 6 * 8;   // 12.6 MB
    int* cntk = (int*)w;          w += 128 * 4;
    int* pcnt = (int*)w;          w += 344 * 4;
    float* gsum   = (float*)w;    w += 128 * 4;
    float* gsumsq = (float*)w;    w += 128 * 4;
    int* hmark    = (int*)w;      w += (size_t)N * 4;
    float* pooled = (float*)w;    w += (size_t)NB * CC * 4;
    size_t zbytes = (size_t)(w - zero0);
    // ---- written-before-read region ----
    float* meanv = (float*)w;     w += 128 * 4;
    float* rsv   = (float*)w;     w += 128 * 4;
    float* c0v   = (float*)w;     w += 128 * 4;
    int* ucode   = (int*)w;       w += (size_t)N * 4;
    int* slotA   = (int*)w;       w += (size_t)N * 4;
    int* hidx    = (int*)w;       w += (size_t)N * 4;
    int* bkUid   = (int*)w;       w += (size_t)KK * CAPK * 4;
    int* bkP     = (int*)w;       w += (size_t)KK * CAPK * 4;
    int* pairPack= (int*)w;       w += (size_t)PP * CAPP * 4;
    float* acc   = (float*)w;     w += (size_t)N * CC * 4;

    hipMemsetAsync(tabB, 0xFF, ffbytes, stream);
    hipMemsetAsync(zero0, 0, zbytes, stream);

    k_build  <<<(Nv + 255) / 256, 256, 0, stream>>>((const int4*)spc, tabB, colKV, colBM, ncol, Nv);
    k_insertA<<<(N + 255) / 256, 256, 0, stream>>>(gp, tabA, slotA, N);
    k_assignUid<<<TASLOTS / 256, 256, 0, stream>>>(tabA, ucode, nq);
    long tot = (long)N * 25;
    k_probe  <<<(unsigned)((tot + 255) / 256), 256, 0, stream>>>(ucode, colKV, colBM, tabB,
                                                                 (const int4*)spc,
                                                                 hmark, cntk, bkUid, bkP, nq, N);
    k_compact<<<(N + 255) / 256, 256, 0, stream>>>(hmark, hidx, acc, nh, nq);
    k_conv   <<<dim3(KK, 2, 4), 256, 0, stream>>>(spf, W1, cntk, bkUid, bkP, hidx, acc);
    k_stats  <<<256, 256, 0, stream>>>(acc, gsum, gsumsq, nh);
    k_bn1    <<<1, 128, 0, stream>>>(gsum, gsumsq, g1, b1, meanv, rsv, c0v, nq);
    k_dx     <<<1024, 256, 0, stream>>>(acc, meanv, rsv, c0v, g1, b1, nh);
    k_pairs  <<<(N + 255) / 256, 256, 0, stream>>>(slotA, tabA, hidx, pcnt, pairPack, N);
    k_pool   <<<dim3(PP, 2, 2), 256, 0, stream>>>(acc, W2, pcnt, pairPack, pooled);
    k_bn2    <<<CC, 64, 0, stream>>>(pooled, g2, b2, out, NB);
}

// Round 4
// 504.927 us; speedup vs baseline: 1.5652x; 1.0775x over previous
//
#include <hip/hip_runtime.h>
#include <math.h>

#define GG     384
#define HALFG  192
#define SZc    384
#define SYZc   147456
#define SXYZc  56623104
#define CC     128
#define PP     343
#define KK     125
// tabB: u32 tag-table for sp voxels, 2^20 slots = 4 MB
#define TBSLOTS (1 << 20)
#define TBMASK  (TBSLOTS - 1)
#define EMPTYB  0xFFFFFFFFu
// colKV: u32 exact-code table (b,x,y), 2^19 slots = 2 MB; cid == slot
#define CHSLOTS (1 << 19)
#define CHMASK  (CHSLOTS - 1)
#define EMPTYU  0xFFFFFFFFu
// tabA: int2 dedupe table for grid voxels, 2^19 slots = 4 MB
#define TASLOTS (1 << 19)
#define TAMASK  (TASLOTS - 1)
#define NBLKA   (TASLOTS / 256)   // 2048
#define CAPK   2048
#define CAPP   1024
#define EPSc   1e-5f

typedef unsigned long long u64;

__device__ __forceinline__ unsigned hash32(int code) {
    unsigned h = (unsigned)code;
    h ^= h >> 16; h *= 0x7feb352du;
    h ^= h >> 15; h *= 0x846ca68bu;
    h ^= h >> 16;
    return h;
}

// ---- build: sp-voxel tag table + column table (cid = slot) + column z-bitmaps ----
__global__ void k_build(const int4* __restrict__ spc4, unsigned* tabB,
                        unsigned* colKV, u64* colBM, int Nv) {
    int i = blockIdx.x * 256 + threadIdx.x;
    if (i >= Nv) return;
    int4 s = spc4[i];
    int b = s.x;
    int x = (s.y >> 1) + HALFG;
    int y = (s.z >> 1) + HALFG;
    int z = (s.w >> 1) + HALFG;
    int code = b * SXYZc + x * SYZc + y * SZc + z;
    // 1) exact-row tag table
    unsigned h = hash32(code);
    unsigned slot = h & TBMASK;
    unsigned val = ((h >> 18) << 18) | (unsigned)i;
    while (true) {
        unsigned old = atomicCAS(&tabB[slot], EMPTYB, val);
        if (old == EMPTYB) break;
        slot = (slot + 1) & TBMASK;
    }
    // 2) column table: cid = winning slot (no counter)
    unsigned ccode = (unsigned)((b * GG + x) * GG + y);   // < 2^20
    unsigned cs = hash32((int)ccode) & CHMASK;
    int cid;
    while (true) {
        unsigned old = atomicCAS(&colKV[cs], EMPTYU, ccode);
        if (old == EMPTYU || old == ccode) { cid = (int)cs; break; }
        cs = (cs + 1) & CHMASK;
    }
    atomicOr(&colBM[(size_t)cid * 6 + (z >> 6)], 1ull << (z & 63));
}

// ---- voxelize grid points, insert into dedupe hash, remember slot ----
__global__ void k_insertA(const float* __restrict__ gp, int2* tabA, int* slotA, int N) {
    int i = blockIdx.x * 256 + threadIdx.x;
    if (i >= N) return;
    float4 g = ((const float4*)gp)[i];
    int b = (int)g.x;
    int vx = (int)floorf(g.y / 0.08f); vx = min(max(vx, -(HALFG - 1)), HALFG - 1);
    int vy = (int)floorf(g.z / 0.08f); vy = min(max(vy, -(HALFG - 1)), HALFG - 1);
    int vz = (int)floorf(g.w / 0.08f); vz = min(max(vz, -(HALFG - 1)), HALFG - 1);
    int code = b * SXYZc + (vx + HALFG) * SYZc + (vy + HALFG) * SZc + (vz + HALFG);
    unsigned h = hash32(code) & TAMASK;
    while (true) {
        int old = atomicCAS(&tabA[h].x, -1, code);
        if (old == -1 || old == code) break;
        h = (h + 1) & TAMASK;
    }
    slotA[i] = (int)h;
}

// ---- uid assignment, phase 1: per-block occupied counts (no atomics) ----
__global__ void k_cntA(const int2* __restrict__ tabA, int* blockCnt) {
    int s = blockIdx.x * 256 + threadIdx.x;
    bool occ = tabA[s].x != -1;
    u64 m = __ballot(occ);
    __shared__ int ws[4];
    if ((threadIdx.x & 63) == 0) ws[threadIdx.x >> 6] = __popcll(m);
    __syncthreads();
    if (threadIdx.x == 0) blockCnt[blockIdx.x] = ws[0] + ws[1] + ws[2] + ws[3];
}

// ---- phase 2: one-block scan of 2048 block counts -> bases + total ----
__global__ void k_scanA(const int* __restrict__ blockCnt, int* blockBase, int* nq) {
    __shared__ int part[256];
    int t = threadIdx.x;
    int c[8]; int s = 0;
    #pragma unroll
    for (int i = 0; i < 8; i++) { c[i] = blockCnt[t * 8 + i]; s += c[i]; }
    part[t] = s;
    __syncthreads();
    for (int o = 1; o < 256; o <<= 1) {
        int v = (t >= o) ? part[t - o] : 0;
        __syncthreads();
        part[t] += v;
        __syncthreads();
    }
    int b = part[t] - s;          // exclusive base for this thread's 8 blocks
    #pragma unroll
    for (int i = 0; i < 8; i++) { blockBase[t * 8 + i] = b; b += c[i]; }
    if (t == 255) *nq = part[255];
}

// ---- phase 3: assign uids deterministically ----
__global__ void k_asgA(int2* tabA, int* __restrict__ ucode,
                       const int* __restrict__ blockBase) {
    int s = blockIdx.x * 256 + threadIdx.x;
    int c = tabA[s].x;
    bool occ = (c != -1);
    u64 m = __ballot(occ);
    int lane = threadIdx.x & 63, wv = threadIdx.x >> 6;
    __shared__ int wcnt[4];
    if (lane == 0) wcnt[wv] = __popcll(m);
    __syncthreads();
    int base = blockBase[blockIdx.x];
    for (int i = 0; i < wv; i++) base += wcnt[i];
    if (occ) {
        int uid = base + __popcll(m & ((1ull << lane) - 1ull));
        tabA[s].y = uid;
        ucode[uid] = c;
    }
}

// ---- probe: 25 columns per uid, 5-bit z-window from bitmap, exact resolve on hit ----
__global__ void k_probe(const int* __restrict__ ucode, const unsigned* __restrict__ colKV,
                        const u64* __restrict__ colBM, const unsigned* __restrict__ tabB,
                        const int4* __restrict__ spc4,
                        int* hmark, int* cntk, int* bkUid, int* bkP,
                        const int* __restrict__ nqp, int N) {
    unsigned tid = blockIdx.x * 256u + threadIdx.x;
    if (tid >= (unsigned)N * 25u) return;
    unsigned uid = tid / 25u;
    if (uid >= (unsigned)(*nqp)) return;
    int c = (int)(tid - uid * 25u);      // c = dx*5 + dy
    unsigned code = (unsigned)ucode[uid];
    unsigned b = code / SXYZc; unsigned rem = code - b * SXYZc;
    int x = (int)(rem / SYZc); rem -= (unsigned)x * SYZc;
    int y = (int)(rem / SZc);
    int z = (int)(rem - (unsigned)y * SZc);
    int dx = c / 5, dy = c - dx * 5;
    int cx = x + dx - 2, cy = y + dy - 2;
    if ((unsigned)cx >= GG || (unsigned)cy >= GG) return;
    unsigned ccode = (unsigned)(((int)b * GG + cx) * GG + cy);
    unsigned cs = hash32((int)ccode) & CHMASK;
    int cid = -1;
    while (true) {
        unsigned e = colKV[cs];
        if (e == EMPTYU) return;                       // column unoccupied
        if (e == ccode) { cid = (int)cs; break; }
        cs = (cs + 1) & CHMASK;
    }
    int lo = max(z - 2, 0);
    int hi = min(z + 2, GG - 1);
    int width = hi - lo + 1;
    int i0 = lo >> 6, sh = lo & 63;
    const u64* bm = colBM + (size_t)cid * 6;
    u64 w = bm[i0] >> sh;
    if (sh + width > 64) w |= bm[i0 + 1] << (64 - sh);
    unsigned bits = (unsigned)(w & ((1ull << width) - 1ull));
    if (bits == 0) return;
    hmark[uid] = 1;
    int zbase = z - 2;
    while (bits) {
        int j = __builtin_ctz(bits);
        bits &= bits - 1;
        int tz = lo + j;
        int dz = tz - zbase;                           // 0..4
        int k = c * 5 + dz;
        int tcode = (int)b * SXYZc + cx * SYZc + cy * SZc + tz;
        unsigned h = hash32(tcode);
        unsigned slot = h & TBMASK;
        unsigned tag = h >> 18;
        while (true) {
            unsigned v = tabB[slot];
            if (v == EMPTYB) break;                    // can't happen (bitmap says exists)
            if ((v >> 18) == tag) {
                int row = (int)(v & 0x3FFFFu);
                int4 s = spc4[row];
                int rcode = s.x * SXYZc + ((s.y >> 1) + HALFG) * SYZc
                          + ((s.z >> 1) + HALFG) * SZc + ((s.w >> 1) + HALFG);
                if (rcode == tcode) {
                    int pos = atomicAdd(&cntk[k], 1);
                    if (pos < CAPK) { bkUid[k * CAPK + pos] = (int)uid; bkP[k * CAPK + pos] = row; }
                    break;
                }
            }
            slot = (slot + 1) & TBMASK;
        }
    }
}

// ---- zero acc rows of hit uids (no counter; acc indexed by uid) ----
__global__ void k_zeroAcc(const int* __restrict__ hmark, float* acc, int N) {
    int u = blockIdx.x * 256 + threadIdx.x;
    if (u >= N || !hmark[u]) return;
    float4* a4 = (float4*)(acc + (size_t)u * CC);
    float4 z4 = make_float4(0.f, 0.f, 0.f, 0.f);
    #pragma unroll
    for (int c = 0; c < CC / 4; c++) a4[c] = z4;
}

// ---- sparse conv: hits grouped by kernel offset, acc indexed by uid ----
__global__ __launch_bounds__(256) void k_conv(const float* __restrict__ spf,
        const float* __restrict__ W1, const int* __restrict__ cntk,
        const int* __restrict__ bkUid, const int* __restrict__ bkP, float* acc) {
    int k = blockIdx.x;
    int cob = blockIdx.y * 64;
    int t = threadIdx.x;
    int co = cob + (t & 63);
    int lane = t >> 6;                  // 0..3, 8 rows each
    int cnt = min(cntk[k], CAPK);
    __shared__ float fs[32][CC];
    __shared__ int hrS[32];
    const float* Wk = W1 + (size_t)k * CC * CC;
    for (int tile = blockIdx.z * 32; tile < cnt; tile += 32 * gridDim.z) {
        int nt = min(32, cnt - tile);
        if (t < nt) hrS[t] = bkUid[k * CAPK + tile + t];
        for (int e = t; e < 32 * CC; e += 256) {
            int r = e >> 7, cc = e & 127;
            fs[r][cc] = (r < nt) ? spf[(size_t)bkP[k * CAPK + tile + r] * CC + cc] : 0.f;
        }
        __syncthreads();
        float a[8] = {0.f, 0.f, 0.f, 0.f, 0.f, 0.f, 0.f, 0.f};
        for (int ci = 0; ci < CC; ci++) {
            float wv = Wk[(size_t)ci * CC + co];
            #pragma unroll
            for (int j = 0; j < 8; j++) a[j] += fs[lane * 8 + j][ci] * wv;
        }
        #pragma unroll
        for (int j = 0; j < 8; j++) {
            int r = lane * 8 + j;
            if (r < nt) atomicAdd(&acc[(size_t)hrS[r] * CC + co], a[j]);
        }
        __syncthreads();
    }
}

// ---- BN1 stats over hit rows ----
__global__ void k_stats(const float* __restrict__ acc, const int* __restrict__ hmark,
                        float* gsum, float* gsumsq, const int* __restrict__ nqp) {
    int t = threadIdx.x; int c = t & 127; int half = t >> 7;
    int nq = *nqp;
    float s = 0.f, s2 = 0.f;
    for (int r = blockIdx.x * 2 + half; r < nq; r += gridDim.x * 2) {
        if (!hmark[r]) continue;
        float v = acc[(size_t)r * CC + c];
        s += v; s2 += v * v;
    }
    __shared__ float red[256];
    red[t] = s; __syncthreads();
    if (half == 0) atomicAdd(&gsum[c], s + red[t + 128]);
    __syncthreads();
    red[t] = s2; __syncthreads();
    if (half == 0) atomicAdd(&gsumsq[c], s2 + red[t + 128]);
}

// ---- mean/rs/c0 per channel (base path cancels in BN2) ----
__global__ void k_bn1(const float* __restrict__ gsum, const float* __restrict__ gsumsq,
                      const float* __restrict__ g1, const float* __restrict__ b1,
                      float* meanv, float* rsv, float* c0v, const int* __restrict__ nqp) {
    int t = threadIdx.x;   // 128
    float n = (float)max(*nqp, 1);
    float mean = gsum[t] / n;
    float var = gsumsq[t] / n - mean * mean;
    float rs = 1.0f / sqrtf(var + EPSc);
    float c0 = (0.f - mean) * rs * g1[t] + b1[t];
    c0 = c0 > 0.f ? c0 : expm1f(c0);
    meanv[t] = mean; rsv[t] = rs; c0v[t] = c0;
}

// ---- dx = elu(bn(acc)) - c0 on hit rows ----
__global__ void k_dx(float* acc, const int* __restrict__ hmark,
                     const float* __restrict__ meanv, const float* __restrict__ rsv,
                     const float* __restrict__ c0v, const float* __restrict__ g1,
                     const float* __restrict__ b1, const int* __restrict__ nqp) {
    int total = (*nqp) * CC;
    for (int e = blockIdx.x * 256 + threadIdx.x; e < total; e += gridDim.x * 256) {
        int r = e >> 7;
        if (!hmark[r]) continue;
        int c = e & 127;
        float v = acc[e];
        float x = (v - meanv[c]) * rsv[c] * g1[c] + b1[c];
        x = x > 0.f ? x : expm1f(x);
        acc[e] = x - c0v[c];
    }
}

// ---- build sparse (b,p,uid) pairs bucketed by p ----
__global__ void k_pairs(const int* __restrict__ slotA, const int2* __restrict__ tabA,
                        const int* __restrict__ hmark, int* pcnt, int* pairPack, int N) {
    int i = blockIdx.x * 256 + threadIdx.x;
    if (i >= N) return;
    int uid = tabA[slotA[i]].y;
    if (!hmark[uid]) return;
    int b = i / PP;
    int p = i - b * PP;
    int pos = atomicAdd(&pcnt[p], 1);
    if (pos < CAPP) pairPack[p * CAPP + pos] = (b << 18) | uid;
}

// ---- sparse pooling: pairs grouped by p ----
__global__ __launch_bounds__(256) void k_pool(const float* __restrict__ acc,
        const float* __restrict__ W2, const int* __restrict__ pcnt,
        const int* __restrict__ pairPack, float* pooled) {
    int p = blockIdx.x;
    int cob = blockIdx.y * 64;
    int t = threadIdx.x;
    int co = cob + (t & 63);
    int lane = t >> 6;
    int cnt = min(pcnt[p], CAPP);
    __shared__ float fs[32][CC];
    __shared__ int bS[32];
    const float* Wp = W2 + (size_t)p * CC * CC;
    for (int tile = blockIdx.z * 32; tile < cnt; tile += 32 * gridDim.z) {
        int nt = min(32, cnt - tile);
        if (t < nt) bS[t] = pairPack[p * CAPP + tile + t] >> 18;
        for (int e = t; e < 32 * CC; e += 256) {
            int r = e >> 7, cc = e & 127;
            float v = 0.f;
            if (r < nt) {
                int uid = pairPack[p * CAPP + tile + r] & 0x3FFFF;
                v = acc[(size_t)uid * CC + cc];
            }
            fs[r][cc] = v;
        }
        __syncthreads();
        float a[8] = {0.f, 0.f, 0.f, 0.f, 0.f, 0.f, 0.f, 0.f};
        for (int ci = 0; ci < CC; ci++) {
            float wv = Wp[(size_t)ci * CC + co];
            #pragma unroll
            for (int j = 0; j < 8; j++) a[j] += fs[lane * 8 + j][ci] * wv;
        }
        #pragma unroll
        for (int j = 0; j < 8; j++) {
            int r = lane * 8 + j;
            if (r < nt) atomicAdd(&pooled[(size_t)bS[r] * CC + co], a[j]);
        }
        __syncthreads();
    }
}

// ---- final BN over 512 rois ----
__global__ void k_bn2(const float* __restrict__ pooled, const float* __restrict__ g2,
                      const float* __restrict__ b2, float* out, int NB) {
    int d = blockIdx.x; int t = threadIdx.x;   // 64 threads = 1 wave
    float s = 0.f;
    for (int b = t; b < NB; b += 64) s += pooled[(size_t)b * CC + d];
    for (int o = 32; o >= 1; o >>= 1) s += __shfl_xor(s, o, 64);
    float mean = s / (float)NB;
    float s2 = 0.f;
    for (int b = t; b < NB; b += 64) { float v = pooled[(size_t)b * CC + d] - mean; s2 += v * v; }
    for (int o = 32; o >= 1; o >>= 1) s2 += __shfl_xor(s2, o, 64);
    float rs = 1.0f / sqrtf(s2 / (float)NB + EPSc);
    float gg = g2[d], bb = b2[d];
    for (int b = t; b < NB; b += 64)
        out[(size_t)b * CC + d] = (pooled[(size_t)b * CC + d] - mean) * rs * gg + bb;
}

extern "C" void kernel_launch(void* const* d_in, const int* in_sizes, int n_in,
                              void* d_out, int out_size, void* d_ws, size_t ws_size,
                              hipStream_t stream) {
    (void)n_in; (void)out_size; (void)ws_size;
    const int*   spc = (const int*)d_in[0];
    const float* spf = (const float*)d_in[1];
    const float* gp  = (const float*)d_in[2];
    const float* W1  = (const float*)d_in[3];
    const float* g1  = (const float*)d_in[4];
    const float* b1  = (const float*)d_in[5];
    const float* W2  = (const float*)d_in[6];
    const float* g2  = (const float*)d_in[7];
    const float* b2  = (const float*)d_in[8];
    int Nv = in_sizes[0] / 4;
    int N  = in_sizes[2] / 4;
    int NB = N / PP;
    float* out = (float*)d_out;

    char* w = (char*)d_ws;
    // ---- 0xFF-init region (one memset) ----
    unsigned* tabB = (unsigned*)w; w += (size_t)TBSLOTS * 4;   // 4 MB
    unsigned* colKV = (unsigned*)w; w += (size_t)CHSLOTS * 4;  // 2 MB
    int2*     tabA = (int2*)w;     w += (size_t)TASLOTS * 8;   // 4 MB
    size_t ffbytes = (size_t)(w - (char*)d_ws);
    // ---- zero-init region (one memset) ----
    char* zero0 = w;
    int* nq   = (int*)w;          w += 64;
    u64* colBM = (u64*)w;         w += (size_t)CHSLOTS * 6 * 8;  // 24 MB
    int* cntk = (int*)w;          w += 128 * 4;
    int* pcnt = (int*)w;          w += 344 * 4;
    float* gsum   = (float*)w;    w += 128 * 4;
    float* gsumsq = (float*)w;    w += 128 * 4;
    int* hmark    = (int*)w;      w += (size_t)N * 4;
    float* pooled = (float*)w;    w += (size_t)NB * CC * 4;
    size_t zbytes = (size_t)(w - zero0);
    // ---- written-before-read region ----
    float* meanv = (float*)w;     w += 128 * 4;
    float* rsv   = (float*)w;     w += 128 * 4;
    float* c0v   = (float*)w;     w += 128 * 4;
    int* blockCnt  = (int*)w;     w += NBLKA * 4;
    int* blockBase = (int*)w;     w += NBLKA * 4;
    int* ucode   = (int*)w;       w += (size_t)N * 4;
    int* slotA   = (int*)w;       w += (size_t)N * 4;
    int* bkUid   = (int*)w;       w += (size_t)KK * CAPK * 4;
    int* bkP     = (int*)w;       w += (size_t)KK * CAPK * 4;
    int* pairPack= (int*)w;       w += (size_t)PP * CAPP * 4;
    float* acc   = (float*)w;     w += (size_t)N * CC * 4;

    hipMemsetAsync(tabB, 0xFF, ffbytes, stream);
    hipMemsetAsync(zero0, 0, zbytes, stream);

    k_build  <<<(Nv + 255) / 256, 256, 0, stream>>>((const int4*)spc, tabB, colKV, colBM, Nv);
    k_insertA<<<(N + 255) / 256, 256, 0, stream>>>(gp, tabA, slotA, N);
    k_cntA   <<<NBLKA, 256, 0, stream>>>(tabA, blockCnt);
    k_scanA  <<<1, 256, 0, stream>>>(blockCnt, blockBase, nq);
    k_asgA   <<<NBLKA, 256, 0, stream>>>(tabA, ucode, blockBase);
    long tot = (long)N * 25;
    k_probe  <<<(unsigned)((tot + 255) / 256), 256, 0, stream>>>(ucode, colKV, colBM, tabB,
                                                                 (const int4*)spc,
                                                                 hmark, cntk, bkUid, bkP, nq, N);
    k_zeroAcc<<<(N + 255) / 256, 256, 0, stream>>>(hmark, acc, N);
    k_conv   <<<dim3(KK, 2, 4), 256, 0, stream>>>(spf, W1, cntk, bkUid, bkP, acc);
    k_stats  <<<256, 256, 0, stream>>>(acc, hmark, gsum, gsumsq, nq);
    k_bn1    <<<1, 128, 0, stream>>>(gsum, gsumsq, g1, b1, meanv, rsv, c0v, nq);
    k_dx     <<<1024, 256, 0, stream>>>(acc, hmark, meanv, rsv, c0v, g1, b1, nq);
    k_pairs  <<<(N + 255) / 256, 256, 0, stream>>>(slotA, tabA, hmark, pcnt, pairPack, N);
    k_pool   <<<dim3(PP, 2, 2), 256, 0, stream>>>(acc, W2, pcnt, pairPack, pooled);
    k_bn2    <<<CC, 64, 0, stream>>>(pooled, g2, b2, out, NB);
}

// Round 5
// 449.619 us; speedup vs baseline: 1.7578x; 1.1230x over previous
//
#include <hip/hip_runtime.h>
#include <math.h>

#define GG     384
#define HALFG  192
#define SZc    384
#define SYZc   147456
#define SXYZc  56623104
#define CC     128
#define PP     343
#define KK     125
// tabB: u32 tag-table for sp voxels, 2^20 slots = 4 MB
#define TBSLOTS (1 << 20)
#define TBMASK  (TBSLOTS - 1)
#define EMPTYB  0xFFFFFFFFu
// colKV: u32 exact-code table (b,x,y), 2^19 slots = 2 MB; cid == slot
#define CHSLOTS (1 << 19)
#define CHMASK  (CHSLOTS - 1)
#define EMPTYU  0xFFFFFFFFu
// tabA: int2 dedupe table for grid voxels, 2^19 slots = 4 MB
#define TASLOTS (1 << 19)
#define TAMASK  (TASLOTS - 1)
#define NBLKA   (TASLOTS / 256)   // 2048
#define CAPK   2048
#define CAPP   1024
#define EPSc   1e-5f

typedef unsigned long long u64;

__device__ __forceinline__ unsigned hash32(int code) {
    unsigned h = (unsigned)code;
    h ^= h >> 16; h *= 0x7feb352du;
    h ^= h >> 15; h *= 0x846ca68bu;
    h ^= h >> 16;
    return h;
}

// ---- build: sp-voxel tag table + column table (cid = slot) + column z-bitmaps ----
__global__ void k_build(const int4* __restrict__ spc4, unsigned* tabB,
                        unsigned* colKV, u64* colBM, int Nv) {
    int i = blockIdx.x * 256 + threadIdx.x;
    if (i >= Nv) return;
    int4 s = spc4[i];
    int b = s.x;
    int x = (s.y >> 1) + HALFG;
    int y = (s.z >> 1) + HALFG;
    int z = (s.w >> 1) + HALFG;
    int code = b * SXYZc + x * SYZc + y * SZc + z;
    unsigned h = hash32(code);
    unsigned slot = h & TBMASK;
    unsigned val = ((h >> 18) << 18) | (unsigned)i;
    while (true) {
        unsigned old = atomicCAS(&tabB[slot], EMPTYB, val);
        if (old == EMPTYB) break;
        slot = (slot + 1) & TBMASK;
    }
    unsigned ccode = (unsigned)((b * GG + x) * GG + y);   // < 2^20
    unsigned cs = hash32((int)ccode) & CHMASK;
    int cid;
    while (true) {
        unsigned old = atomicCAS(&colKV[cs], EMPTYU, ccode);
        if (old == EMPTYU || old == ccode) { cid = (int)cs; break; }
        cs = (cs + 1) & CHMASK;
    }
    atomicOr(&colBM[(size_t)cid * 6 + (z >> 6)], 1ull << (z & 63));
}

// ---- voxelize grid points, insert into dedupe hash, remember slot ----
__global__ void k_insertA(const float* __restrict__ gp, int2* tabA, int* slotA, int N) {
    int i = blockIdx.x * 256 + threadIdx.x;
    if (i >= N) return;
    float4 g = ((const float4*)gp)[i];
    int b = (int)g.x;
    int vx = (int)floorf(g.y / 0.08f); vx = min(max(vx, -(HALFG - 1)), HALFG - 1);
    int vy = (int)floorf(g.z / 0.08f); vy = min(max(vy, -(HALFG - 1)), HALFG - 1);
    int vz = (int)floorf(g.w / 0.08f); vz = min(max(vz, -(HALFG - 1)), HALFG - 1);
    int code = b * SXYZc + (vx + HALFG) * SYZc + (vy + HALFG) * SZc + (vz + HALFG);
    unsigned h = hash32(code) & TAMASK;
    while (true) {
        int old = atomicCAS(&tabA[h].x, -1, code);
        if (old == -1 || old == code) break;
        h = (h + 1) & TAMASK;
    }
    slotA[i] = (int)h;
}

// ---- uid assignment, phase 1: per-block occupied counts ----
__global__ void k_cntA(const int2* __restrict__ tabA, int* blockCnt) {
    int s = blockIdx.x * 256 + threadIdx.x;
    bool occ = tabA[s].x != -1;
    u64 m = __ballot(occ);
    __shared__ int ws[4];
    if ((threadIdx.x & 63) == 0) ws[threadIdx.x >> 6] = __popcll(m);
    __syncthreads();
    if (threadIdx.x == 0) blockCnt[blockIdx.x] = ws[0] + ws[1] + ws[2] + ws[3];
}

// ---- phase 2: one-block scan of 2048 block counts -> bases + total ----
__global__ void k_scanA(const int* __restrict__ blockCnt, int* blockBase, int* nq) {
    __shared__ int part[256];
    int t = threadIdx.x;
    int c[8]; int s = 0;
    #pragma unroll
    for (int i = 0; i < 8; i++) { c[i] = blockCnt[t * 8 + i]; s += c[i]; }
    part[t] = s;
    __syncthreads();
    for (int o = 1; o < 256; o <<= 1) {
        int v = (t >= o) ? part[t - o] : 0;
        __syncthreads();
        part[t] += v;
        __syncthreads();
    }
    int b = part[t] - s;
    #pragma unroll
    for (int i = 0; i < 8; i++) { blockBase[t * 8 + i] = b; b += c[i]; }
    if (t == 255) *nq = part[255];
}

// ---- phase 3: assign uids deterministically ----
__global__ void k_asgA(int2* tabA, int* __restrict__ ucode,
                       const int* __restrict__ blockBase) {
    int s = blockIdx.x * 256 + threadIdx.x;
    int c = tabA[s].x;
    bool occ = (c != -1);
    u64 m = __ballot(occ);
    int lane = threadIdx.x & 63, wv = threadIdx.x >> 6;
    __shared__ int wcnt[4];
    if (lane == 0) wcnt[wv] = __popcll(m);
    __syncthreads();
    int base = blockBase[blockIdx.x];
    for (int i = 0; i < wv; i++) base += wcnt[i];
    if (occ) {
        int uid = base + __popcll(m & ((1ull << lane) - 1ull));
        tabA[s].y = uid;
        ucode[uid] = c;
    }
}

// ---- probe: 25 columns per uid, 5-bit z-window from bitmap, exact resolve on hit ----
__global__ void k_probe(const int* __restrict__ ucode, const unsigned* __restrict__ colKV,
                        const u64* __restrict__ colBM, const unsigned* __restrict__ tabB,
                        const int4* __restrict__ spc4,
                        int* hmark, int* cntk, int* bkUid, int* bkP,
                        const int* __restrict__ nqp, int N) {
    unsigned tid = blockIdx.x * 256u + threadIdx.x;
    if (tid >= (unsigned)N * 25u) return;
    unsigned uid = tid / 25u;
    if (uid >= (unsigned)(*nqp)) return;
    int c = (int)(tid - uid * 25u);      // c = dx*5 + dy
    unsigned code = (unsigned)ucode[uid];
    unsigned b = code / SXYZc; unsigned rem = code - b * SXYZc;
    int x = (int)(rem / SYZc); rem -= (unsigned)x * SYZc;
    int y = (int)(rem / SZc);
    int z = (int)(rem - (unsigned)y * SZc);
    int dx = c / 5, dy = c - dx * 5;
    int cx = x + dx - 2, cy = y + dy - 2;
    if ((unsigned)cx >= GG || (unsigned)cy >= GG) return;
    unsigned ccode = (unsigned)(((int)b * GG + cx) * GG + cy);
    unsigned cs = hash32((int)ccode) & CHMASK;
    int cid = -1;
    while (true) {
        unsigned e = colKV[cs];
        if (e == EMPTYU) return;
        if (e == ccode) { cid = (int)cs; break; }
        cs = (cs + 1) & CHMASK;
    }
    int lo = max(z - 2, 0);
    int hi = min(z + 2, GG - 1);
    int width = hi - lo + 1;
    int i0 = lo >> 6, sh = lo & 63;
    const u64* bm = colBM + (size_t)cid * 6;
    u64 w = bm[i0] >> sh;
    if (sh + width > 64) w |= bm[i0 + 1] << (64 - sh);
    unsigned bits = (unsigned)(w & ((1ull << width) - 1ull));
    if (bits == 0) return;
    hmark[uid] = 1;
    int zbase = z - 2;
    while (bits) {
        int j = __builtin_ctz(bits);
        bits &= bits - 1;
        int tz = lo + j;
        int dz = tz - zbase;                           // 0..4
        int k = c * 5 + dz;
        int tcode = (int)b * SXYZc + cx * SYZc + cy * SZc + tz;
        unsigned h = hash32(tcode);
        unsigned slot = h & TBMASK;
        unsigned tag = h >> 18;
        while (true) {
            unsigned v = tabB[slot];
            if (v == EMPTYB) break;
            if ((v >> 18) == tag) {
                int row = (int)(v & 0x3FFFFu);
                int4 s = spc4[row];
                int rcode = s.x * SXYZc + ((s.y >> 1) + HALFG) * SYZc
                          + ((s.z >> 1) + HALFG) * SZc + ((s.w >> 1) + HALFG);
                if (rcode == tcode) {
                    int pos = atomicAdd(&cntk[k], 1);
                    if (pos < CAPK) { bkUid[k * CAPK + pos] = (int)uid; bkP[k * CAPK + pos] = row; }
                    break;
                }
            }
            slot = (slot + 1) & TBMASK;
        }
    }
}

// ---- hit-list, phase 1: per-block hit counts ----
__global__ void k_cntH(const int* __restrict__ hmark, int* bcnt, int N) {
    int i = blockIdx.x * 256 + threadIdx.x;
    bool h = (i < N) && hmark[i];
    u64 m = __ballot(h);
    __shared__ int ws[4];
    if ((threadIdx.x & 63) == 0) ws[threadIdx.x >> 6] = __popcll(m);
    __syncthreads();
    if (threadIdx.x == 0) bcnt[blockIdx.x] = ws[0] + ws[1] + ws[2] + ws[3];
}

// ---- phase 2: scan up to 1024 block counts ----
__global__ void k_scanH(const int* __restrict__ bcnt, int* bbase, int* nh, int nbh) {
    __shared__ int part[256];
    int t = threadIdx.x;
    int c[4]; int s = 0;
    #pragma unroll
    for (int i = 0; i < 4; i++) {
        int idx = t * 4 + i;
        c[i] = (idx < nbh) ? bcnt[idx] : 0;
        s += c[i];
    }
    part[t] = s;
    __syncthreads();
    for (int o = 1; o < 256; o <<= 1) {
        int v = (t >= o) ? part[t - o] : 0;
        __syncthreads();
        part[t] += v;
        __syncthreads();
    }
    int b = part[t] - s;
    #pragma unroll
    for (int i = 0; i < 4; i++) {
        int idx = t * 4 + i;
        if (idx < nbh) bbase[idx] = b;
        b += c[i];
    }
    if (t == 255) *nh = part[255];
}

// ---- phase 3: write compact hit list + zero acc rows of hits ----
__global__ void k_asgH(const int* __restrict__ hmark, int* hitList,
                       const int* __restrict__ bbase, float* acc, int N) {
    int i = blockIdx.x * 256 + threadIdx.x;
    bool h = (i < N) && hmark[i];
    u64 m = __ballot(h);
    int lane = threadIdx.x & 63, wv = threadIdx.x >> 6;
    __shared__ int wcnt[4];
    if (lane == 0) wcnt[wv] = __popcll(m);
    __syncthreads();
    int base = bbase[blockIdx.x];
    for (int j = 0; j < wv; j++) base += wcnt[j];
    if (h) {
        int pos = base + __popcll(m & ((1ull << lane) - 1ull));
        hitList[pos] = i;
        float4* a4 = (float4*)(acc + (size_t)i * CC);
        float4 z4 = make_float4(0.f, 0.f, 0.f, 0.f);
        #pragma unroll
        for (int c = 0; c < CC / 4; c++) a4[c] = z4;
    }
}

// ---- sparse conv: hits grouped by kernel offset, acc indexed by uid ----
__global__ __launch_bounds__(256) void k_conv(const float* __restrict__ spf,
        const float* __restrict__ W1, const int* __restrict__ cntk,
        const int* __restrict__ bkUid, const int* __restrict__ bkP, float* acc) {
    int k = blockIdx.x;
    int cob = blockIdx.y * 64;
    int t = threadIdx.x;
    int co = cob + (t & 63);
    int lane = t >> 6;                  // 0..3, 8 rows each
    int cnt = min(cntk[k], CAPK);
    __shared__ float fs[32][CC];
    __shared__ int hrS[32];
    const float* Wk = W1 + (size_t)k * CC * CC;
    for (int tile = blockIdx.z * 32; tile < cnt; tile += 32 * gridDim.z) {
        int nt = min(32, cnt - tile);
        if (t < nt) hrS[t] = bkUid[k * CAPK + tile + t];
        for (int e = t; e < 32 * CC; e += 256) {
            int r = e >> 7, cc = e & 127;
            fs[r][cc] = (r < nt) ? spf[(size_t)bkP[k * CAPK + tile + r] * CC + cc] : 0.f;
        }
        __syncthreads();
        float a[8] = {0.f, 0.f, 0.f, 0.f, 0.f, 0.f, 0.f, 0.f};
        for (int ci = 0; ci < CC; ci++) {
            float wv = Wk[(size_t)ci * CC + co];
            #pragma unroll
            for (int j = 0; j < 8; j++) a[j] += fs[lane * 8 + j][ci] * wv;
        }
        #pragma unroll
        for (int j = 0; j < 8; j++) {
            int r = lane * 8 + j;
            if (r < nt) atomicAdd(&acc[(size_t)hrS[r] * CC + co], a[j]);
        }
        __syncthreads();
    }
}

// ---- BN1 stats over compact hit list ----
__global__ void k_stats(const float* __restrict__ acc, const int* __restrict__ hitList,
                        float* gsum, float* gsumsq, const int* __restrict__ nhp) {
    int t = threadIdx.x; int c = t & 127; int half = t >> 7;
    int nh = *nhp;
    float s = 0.f, s2 = 0.f;
    for (int j = blockIdx.x * 2 + half; j < nh; j += gridDim.x * 2) {
        int r = hitList[j];
        float v = acc[(size_t)r * CC + c];
        s += v; s2 += v * v;
    }
    __shared__ float red[256];
    red[t] = s; __syncthreads();
    if (half == 0) atomicAdd(&gsum[c], s + red[t + 128]);
    __syncthreads();
    red[t] = s2; __syncthreads();
    if (half == 0) atomicAdd(&gsumsq[c], s2 + red[t + 128]);
}

// ---- mean/rs/c0 per channel (base path cancels in BN2) ----
__global__ void k_bn1(const float* __restrict__ gsum, const float* __restrict__ gsumsq,
                      const float* __restrict__ g1, const float* __restrict__ b1,
                      float* meanv, float* rsv, float* c0v, const int* __restrict__ nqp) {
    int t = threadIdx.x;   // 128
    float n = (float)max(*nqp, 1);
    float mean = gsum[t] / n;
    float var = gsumsq[t] / n - mean * mean;
    float rs = 1.0f / sqrtf(var + EPSc);
    float c0 = (0.f - mean) * rs * g1[t] + b1[t];
    c0 = c0 > 0.f ? c0 : expm1f(c0);
    meanv[t] = mean; rsv[t] = rs; c0v[t] = c0;
}

// ---- dx = elu(bn(acc)) - c0 on compact hit rows, float4 ----
__global__ void k_dx(float* acc, const int* __restrict__ hitList,
                     const float* __restrict__ meanv, const float* __restrict__ rsv,
                     const float* __restrict__ c0v, const float* __restrict__ g1,
                     const float* __restrict__ b1, const int* __restrict__ nhp) {
    int total = (*nhp) * 32;
    for (int e = blockIdx.x * 256 + threadIdx.x; e < total; e += gridDim.x * 256) {
        int r = hitList[e >> 5];
        int c4 = (e & 31) * 4;
        float4* p = (float4*)(acc + (size_t)r * CC + c4);
        float4 v = *p;
        float o[4] = {v.x, v.y, v.z, v.w};
        #pragma unroll
        for (int j = 0; j < 4; j++) {
            int c = c4 + j;
            float x = (o[j] - meanv[c]) * rsv[c] * g1[c] + b1[c];
            x = x > 0.f ? x : expm1f(x);
            o[j] = x - c0v[c];
        }
        *p = make_float4(o[0], o[1], o[2], o[3]);
    }
}

// ---- build sparse (b,p,uid) pairs bucketed by p ----
__global__ void k_pairs(const int* __restrict__ slotA, const int2* __restrict__ tabA,
                        const int* __restrict__ hmark, int* pcnt, int* pairPack, int N) {
    int i = blockIdx.x * 256 + threadIdx.x;
    if (i >= N) return;
    int uid = tabA[slotA[i]].y;
    if (!hmark[uid]) return;
    int b = i / PP;
    int p = i - b * PP;
    int pos = atomicAdd(&pcnt[p], 1);
    if (pos < CAPP) pairPack[p * CAPP + pos] = (b << 18) | uid;
}

// ---- sparse pooling: pairs grouped by p ----
__global__ __launch_bounds__(256) void k_pool(const float* __restrict__ acc,
        const float* __restrict__ W2, const int* __restrict__ pcnt,
        const int* __restrict__ pairPack, float* pooled) {
    int p = blockIdx.x;
    int cob = blockIdx.y * 64;
    int t = threadIdx.x;
    int co = cob + (t & 63);
    int lane = t >> 6;
    int cnt = min(pcnt[p], CAPP);
    __shared__ float fs[32][CC];
    __shared__ int bS[32];
    const float* Wp = W2 + (size_t)p * CC * CC;
    for (int tile = blockIdx.z * 32; tile < cnt; tile += 32 * gridDim.z) {
        int nt = min(32, cnt - tile);
        if (t < nt) bS[t] = pairPack[p * CAPP + tile + t] >> 18;
        for (int e = t; e < 32 * CC; e += 256) {
            int r = e >> 7, cc = e & 127;
            float v = 0.f;
            if (r < nt) {
                int uid = pairPack[p * CAPP + tile + r] & 0x3FFFF;
                v = acc[(size_t)uid * CC + cc];
            }
            fs[r][cc] = v;
        }
        __syncthreads();
        float a[8] = {0.f, 0.f, 0.f, 0.f, 0.f, 0.f, 0.f, 0.f};
        for (int ci = 0; ci < CC; ci++) {
            float wv = Wp[(size_t)ci * CC + co];
            #pragma unroll
            for (int j = 0; j < 8; j++) a[j] += fs[lane * 8 + j][ci] * wv;
        }
        #pragma unroll
        for (int j = 0; j < 8; j++) {
            int r = lane * 8 + j;
            if (r < nt) atomicAdd(&pooled[(size_t)bS[r] * CC + co], a[j]);
        }
        __syncthreads();
    }
}

// ---- final BN over 512 rois ----
__global__ void k_bn2(const float* __restrict__ pooled, const float* __restrict__ g2,
                      const float* __restrict__ b2, float* out, int NB) {
    int d = blockIdx.x; int t = threadIdx.x;   // 64 threads = 1 wave
    float s = 0.f;
    for (int b = t; b < NB; b += 64) s += pooled[(size_t)b * CC + d];
    for (int o = 32; o >= 1; o >>= 1) s += __shfl_xor(s, o, 64);
    float mean = s / (float)NB;
    float s2 = 0.f;
    for (int b = t; b < NB; b += 64) { float v = pooled[(size_t)b * CC + d] - mean; s2 += v * v; }
    for (int o = 32; o >= 1; o >>= 1) s2 += __shfl_xor(s2, o, 64);
    float rs = 1.0f / sqrtf(s2 / (float)NB + EPSc);
    float gg = g2[d], bb = b2[d];
    for (int b = t; b < NB; b += 64)
        out[(size_t)b * CC + d] = (pooled[(size_t)b * CC + d] - mean) * rs * gg + bb;
}

extern "C" void kernel_launch(void* const* d_in, const int* in_sizes, int n_in,
                              void* d_out, int out_size, void* d_ws, size_t ws_size,
                              hipStream_t stream) {
    (void)n_in; (void)out_size; (void)ws_size;
    const int*   spc = (const int*)d_in[0];
    const float* spf = (const float*)d_in[1];
    const float* gp  = (const float*)d_in[2];
    const float* W1  = (const float*)d_in[3];
    const float* g1  = (const float*)d_in[4];
    const float* b1  = (const float*)d_in[5];
    const float* W2  = (const float*)d_in[6];
    const float* g2  = (const float*)d_in[7];
    const float* b2  = (const float*)d_in[8];
    int Nv = in_sizes[0] / 4;
    int N  = in_sizes[2] / 4;
    int NB = N / PP;
    int NBH = (N + 255) / 256;    // 687 blocks for hit-list phases
    float* out = (float*)d_out;

    char* w = (char*)d_ws;
    // ---- 0xFF-init region (one memset) ----
    unsigned* tabB = (unsigned*)w; w += (size_t)TBSLOTS * 4;   // 4 MB
    unsigned* colKV = (unsigned*)w; w += (size_t)CHSLOTS * 4;  // 2 MB
    int2*     tabA = (int2*)w;     w += (size_t)TASLOTS * 8;   // 4 MB
    size_t ffbytes = (size_t)(w - (char*)d_ws);
    // ---- zero-init region (one memset) ----
    char* zero0 = w;
    int* nq   = (int*)w;  int* nh = nq + 1;  w += 64;
    u64* colBM = (u64*)w;         w += (size_t)CHSLOTS * 6 * 8;  // 24 MB
    int* cntk = (int*)w;          w += 128 * 4;
    int* pcnt = (int*)w;          w += 344 * 4;
    float* gsum   = (float*)w;    w += 128 * 4;
    float* gsumsq = (float*)w;    w += 128 * 4;
    int* hmark    = (int*)w;      w += (size_t)N * 4;
    float* pooled = (float*)w;    w += (size_t)NB * CC * 4;
    size_t zbytes = (size_t)(w - zero0);
    // ---- written-before-read region ----
    float* meanv = (float*)w;     w += 128 * 4;
    float* rsv   = (float*)w;     w += 128 * 4;
    float* c0v   = (float*)w;     w += 128 * 4;
    int* blockCnt  = (int*)w;     w += NBLKA * 4;
    int* blockBase = (int*)w;     w += NBLKA * 4;
    int* bcntH   = (int*)w;       w += 1024 * 4;
    int* bbaseH  = (int*)w;       w += 1024 * 4;
    int* hitList = (int*)w;       w += (size_t)N * 4;
    int* ucode   = (int*)w;       w += (size_t)N * 4;
    int* slotA   = (int*)w;       w += (size_t)N * 4;
    int* bkUid   = (int*)w;       w += (size_t)KK * CAPK * 4;
    int* bkP     = (int*)w;       w += (size_t)KK * CAPK * 4;
    int* pairPack= (int*)w;       w += (size_t)PP * CAPP * 4;
    float* acc   = (float*)w;     w += (size_t)N * CC * 4;

    hipMemsetAsync(tabB, 0xFF, ffbytes, stream);
    hipMemsetAsync(zero0, 0, zbytes, stream);

    k_build  <<<(Nv + 255) / 256, 256, 0, stream>>>((const int4*)spc, tabB, colKV, colBM, Nv);
    k_insertA<<<(N + 255) / 256, 256, 0, stream>>>(gp, tabA, slotA, N);
    k_cntA   <<<NBLKA, 256, 0, stream>>>(tabA, blockCnt);
    k_scanA  <<<1, 256, 0, stream>>>(blockCnt, blockBase, nq);
    k_asgA   <<<NBLKA, 256, 0, stream>>>(tabA, ucode, blockBase);
    long tot = (long)N * 25;
    k_probe  <<<(unsigned)((tot + 255) / 256), 256, 0, stream>>>(ucode, colKV, colBM, tabB,
                                                                 (const int4*)spc,
                                                                 hmark, cntk, bkUid, bkP, nq, N);
    k_cntH   <<<NBH, 256, 0, stream>>>(hmark, bcntH, N);
    k_scanH  <<<1, 256, 0, stream>>>(bcntH, bbaseH, nh, NBH);
    k_asgH   <<<NBH, 256, 0, stream>>>(hmark, hitList, bbaseH, acc, N);
    k_conv   <<<dim3(KK, 2, 4), 256, 0, stream>>>(spf, W1, cntk, bkUid, bkP, acc);
    k_stats  <<<1024, 256, 0, stream>>>(acc, hitList, gsum, gsumsq, nh);
    k_bn1    <<<1, 128, 0, stream>>>(gsum, gsumsq, g1, b1, meanv, rsv, c0v, nq);
    k_dx     <<<512, 256, 0, stream>>>(acc, hitList, meanv, rsv, c0v, g1, b1, nh);
    k_pairs  <<<(N + 255) / 256, 256, 0, stream>>>(slotA, tabA, hmark, pcnt, pairPack, N);
    k_pool   <<<dim3(PP, 2, 2), 256, 0, stream>>>(acc, W2, pcnt, pairPack, pooled);
    k_bn2    <<<CC, 64, 0, stream>>>(pooled, g2, b2, out, NB);
}